// Round 1
// baseline (284.399 us; speedup 1.0000x reference)
//
#include <hip/hip_runtime.h>
#include <stdint.h>

#define NTOK 1024
#define DIM 768
#define NH 12

typedef short bf16x8 __attribute__((ext_vector_type(8)));
typedef float f32x4 __attribute__((ext_vector_type(4)));
typedef uint32_t u32x4 __attribute__((ext_vector_type(4)));

__device__ __forceinline__ unsigned short f2bf(float f) {
  union { float f; uint32_t u; } x; x.f = f;
  uint32_t r = x.u + 0x7FFFu + ((x.u >> 16) & 1u);
  return (unsigned short)(r >> 16);
}
__device__ __forceinline__ float bf2f(unsigned short u) {
  union { uint32_t u; float f; } x; x.u = ((uint32_t)u) << 16;
  return x.f;
}

// ---------------------------------------------------------------------------
// prep: single -> bf16; all weights -> transposed bf16 [n][k] rows
// ---------------------------------------------------------------------------
__global__ __launch_bounds__(256) void prep_k(
    const float* __restrict__ single, const float* __restrict__ Wq,
    const float* __restrict__ Wk, const float* __restrict__ Wv,
    const float* __restrict__ Wqp, const float* __restrict__ Wkp,
    const float* __restrict__ Wvp, const float* __restrict__ Wpo,
    const float* __restrict__ Wo,
    unsigned short* __restrict__ sgl, unsigned short* __restrict__ wqkv,
    unsigned short* __restrict__ wpts, unsigned short* __restrict__ wpo,
    unsigned short* __restrict__ wo)
{
  int idx = blockIdx.x * 256 + threadIdx.x;
  const int S0 = 786432;      // 1024*768 single copy
  const int SW = 589824;      // 768*768
  const int SP = 110592;      // 768*144
  if (idx < S0) { sgl[idx] = f2bf(single[idx]); return; }
  idx -= S0;
  if (idx < 3 * SW) {
    int j = idx / SW, o = idx % SW;
    int n = o / 768, k = o % 768;
    const float* W = (j == 0) ? Wq : (j == 1) ? Wk : Wv;
    wqkv[(size_t)j * SW + o] = f2bf(W[k * 768 + n]);
    return;
  }
  idx -= 3 * SW;
  if (idx < 3 * SP) {
    int j = idx / SP, o = idx % SP;
    int n = o / 768, k = o % 768;
    const float* W = (j == 0) ? Wqp : (j == 1) ? Wkp : Wvp;
    wpts[((size_t)j * 144 + n) * 768 + k] = f2bf(W[k * 144 + n]);
    return;
  }
  idx -= 3 * SP;
  if (idx < SP) {             // Wpo (144x768) -> [768][144]
    int n = idx / 144, k = idx % 144;
    wpo[idx] = f2bf(Wpo[k * 768 + n]);
    return;
  }
  idx -= SP;
  if (idx < SW) {             // Wo -> [768][768]
    int n = idx / 768, k = idx % 768;
    wo[idx] = f2bf(Wo[k * 768 + n]);
    return;
  }
}

// ---------------------------------------------------------------------------
// Generic bf16 MFMA GEMM, C = A(MxK) @ Bt(NxK)^T, 128x128 tile, BK=32,
// 4 waves (2x2 quadrants), reg-prefetch single-LDS-buffer. M == 1024.
// MODE 0: qkv bias-cat(768)   MODE 1: pts bias-cat(144)
// MODE 2: logits epilogue (in-place over pair_bias, bf16)
// MODE 3: S = acc + bpo + ws (bf16 out)   MODE 4: out = acc + bo (f32)
// ---------------------------------------------------------------------------
template <int MODE>
__global__ __launch_bounds__(256) void gemm_bt_k(
    const unsigned short* __restrict__ A, int lda, long long batchA,
    const unsigned short* __restrict__ Bt, int ldb, long long batchB,
    int Nact, int kmax, int ktiles,
    float* __restrict__ outf, unsigned short* __restrict__ outb,
    int ldc, long long batchC,
    const float* __restrict__ p0, const float* __restrict__ p1,
    const float* __restrict__ p2)
{
  __shared__ unsigned short As[128 * 32];
  __shared__ unsigned short Bs[128 * 32];
  const int t = threadIdx.x;
  const int w = t >> 6, lane = t & 63;
  const int wr = w >> 1, wc = w & 1;
  const int lr = lane & 15, lc = lane >> 4;
  const int m0 = blockIdx.x * 128, n0 = blockIdx.y * 128;
  const int z = blockIdx.z;
  const unsigned short* Ab = A + (size_t)z * (size_t)batchA;
  const unsigned short* Bb = Bt + (size_t)z * (size_t)batchB;

  const int s0 = t, s1 = t + 256;
  const int r0 = s0 >> 2, c0 = s0 & 3, r1 = s1 >> 2, c1 = s1 & 3;

  f32x4 acc[4][4] = {};
  u32x4 zz = {0u, 0u, 0u, 0u};
  u32x4 pa0, pa1, pq0, pq1;

#define LOAD_AB(KT)                                                              \
  do {                                                                           \
    int k0_ = (KT) * 32;                                                         \
    int g0_ = k0_ + c0 * 8, g1_ = k0_ + c1 * 8;                                  \
    pa0 = (g0_ < kmax) ? *(const u32x4*)(Ab + (size_t)(m0 + r0) * lda + g0_) : zz; \
    pa1 = (g1_ < kmax) ? *(const u32x4*)(Ab + (size_t)(m0 + r1) * lda + g1_) : zz; \
    pq0 = (g0_ < kmax && (n0 + r0) < Nact)                                       \
              ? *(const u32x4*)(Bb + (size_t)(n0 + r0) * ldb + g0_) : zz;        \
    pq1 = (g1_ < kmax && (n0 + r1) < Nact)                                       \
              ? *(const u32x4*)(Bb + (size_t)(n0 + r1) * ldb + g1_) : zz;        \
  } while (0)

  LOAD_AB(0);
  for (int kt = 0; kt < ktiles; ++kt) {
    __syncthreads();
    ((u32x4*)As)[r0 * 4 + c0] = pa0;
    ((u32x4*)As)[r1 * 4 + c1] = pa1;
    ((u32x4*)Bs)[r0 * 4 + c0] = pq0;
    ((u32x4*)Bs)[r1 * 4 + c1] = pq1;
    __syncthreads();
    if (kt + 1 < ktiles) LOAD_AB(kt + 1);

    bf16x8 af[4], bfr[4];
#pragma unroll
    for (int mi = 0; mi < 4; ++mi) {
      int row = wr * 64 + mi * 16 + lr;
      af[mi] = *(const bf16x8*)(As + (row * 4 + lc) * 8);
    }
#pragma unroll
    for (int ni = 0; ni < 4; ++ni) {
      int row = wc * 64 + ni * 16 + lr;
      bfr[ni] = *(const bf16x8*)(Bs + (row * 4 + lc) * 8);
    }
#pragma unroll
    for (int mi = 0; mi < 4; ++mi)
#pragma unroll
      for (int ni = 0; ni < 4; ++ni)
        acc[mi][ni] = __builtin_amdgcn_mfma_f32_16x16x32_bf16(
            af[mi], bfr[ni], acc[mi][ni], 0, 0, 0);
  }
#undef LOAD_AB

#pragma unroll
  for (int mi = 0; mi < 4; ++mi) {
#pragma unroll
    for (int ni = 0; ni < 4; ++ni) {
#pragma unroll
      for (int r = 0; r < 4; ++r) {
        int row = m0 + wr * 64 + mi * 16 + lc * 4 + r;
        int col = n0 + wc * 64 + ni * 16 + lr;
        if (col < Nact) {
          float v = acc[mi][ni][r];
          if constexpr (MODE == 0) {
            float bias = (col < 768) ? p0[col] : (col < 1536) ? p1[col - 768]
                                                              : p2[col - 1536];
            outf[(size_t)row * ldc + col] = v + bias;
          } else if constexpr (MODE == 1) {
            float bias = (col < 144) ? p0[col] : (col < 288) ? p1[col - 144]
                                                             : p2[col - 288];
            outf[(size_t)row * ldc + col] = v + bias;
          } else if constexpr (MODE == 2) {
            size_t idx = (size_t)z * (size_t)batchC + (size_t)row * ldc + col;
            float pbv = bf2f(outb[idx]);
            float q2v = p0[z * NTOK + row];
            float k2v = p1[z * NTOK + col];
            outb[idx] = f2bf(0.125f * v - 0.0625f * (q2v + k2v) + pbv);
          } else if constexpr (MODE == 3) {
            float sv = v + p0[col] + p1[(size_t)row * 768 + col];
            outb[(size_t)row * ldc + col] = f2bf(sv);
          } else {
            outf[(size_t)row * ldc + col] = v + p0[col];
          }
        }
      }
    }
  }
}

// ---------------------------------------------------------------------------
// rotate: apply per-token rot/trans to raw points; build bf16 operand tensors
// Acat/Bcat [h][n][96] = [q|qpts_g|pad], VcatT [h][80][n] = [v|vpts_g|pad]^T,
// q2k2 [2][12][n].
// ---------------------------------------------------------------------------
__global__ __launch_bounds__(256) void rotate_k(
    const float* __restrict__ qkv, const float* __restrict__ praw,
    const float* __restrict__ rot, const float* __restrict__ trans,
    unsigned short* __restrict__ Acat, unsigned short* __restrict__ Bcat,
    unsigned short* __restrict__ VcatT, float* __restrict__ q2k2)
{
  const int n = blockIdx.x, t = threadIdx.x;
  __shared__ float R[9], T[3], rg[432];
  if (t < 9) R[t] = rot[n * 9 + t];
  if (t >= 9 && t < 12) T[t - 9] = trans[n * 3 + (t - 9)];
  __syncthreads();
  for (int s = t; s < 432; s += 256) {
    int j = s / 144, r = s % 144;
    int h = r / 12, wo = r % 12;
    int e = wo % 3;
    int base = n * 432 + j * 144 + (r - e);
    float d0 = praw[base + 0], d1 = praw[base + 1], d2 = praw[base + 2];
    float val = d0 * R[e] + d1 * R[3 + e] + d2 * R[6 + e] + T[e];
    rg[s] = val;
    unsigned short bv = f2bf(val);
    if (j == 0)      Acat[((size_t)h * NTOK + n) * 96 + 64 + wo] = bv;
    else if (j == 1) Bcat[((size_t)h * NTOK + n) * 96 + 64 + wo] = bv;
    else             VcatT[((size_t)h * 80 + 64 + wo) * NTOK + n] = bv;
  }
  __syncthreads();
  for (int s = t; s < 2304; s += 256) {
    int j = s / 768, c = s % 768;
    int h = c >> 6, cc = c & 63;
    unsigned short bv = f2bf(qkv[(size_t)n * 2304 + s]);
    if (j == 0)      Acat[((size_t)h * NTOK + n) * 96 + cc] = bv;
    else if (j == 1) Bcat[((size_t)h * NTOK + n) * 96 + cc] = bv;
    else             VcatT[((size_t)h * 80 + cc) * NTOK + n] = bv;
  }
  if (t < 240) {
    int h = t / 20, ix = 76 + t % 20;
    Acat[((size_t)h * NTOK + n) * 96 + ix] = 0;
    Bcat[((size_t)h * NTOK + n) * 96 + ix] = 0;
  }
  if (t >= 240 && t < 288) {
    int s = t - 240;
    int h = s / 4, rr = 76 + s % 4;
    VcatT[((size_t)h * 80 + rr) * NTOK + n] = 0;
  }
  if (t < 24) {
    int j = t / 12, h = t % 12;
    float sum = 0.f;
#pragma unroll
    for (int wo = 0; wo < 12; ++wo) {
      float v = rg[j * 144 + h * 12 + wo];
      sum += v * v;
    }
    q2k2[(size_t)(j * NH + h) * NTOK + n] = sum;
  }
}

// ---------------------------------------------------------------------------
// pair_bias: pb[h][n][m] = bf16(pair[n][m][:] . Wpb[:,h] + bpb[h]); 256MB stream
// ---------------------------------------------------------------------------
__global__ __launch_bounds__(256) void pairbias_k(
    const float* __restrict__ pair, const float* __restrict__ Wpb,
    const float* __restrict__ bpb, unsigned short* __restrict__ pb)
{
  __shared__ float wsh[768];
  __shared__ float bb[12];
  const int t = threadIdx.x;
  for (int s = t; s < 768; s += 256) wsh[s] = Wpb[s];
  if (t < 12) bb[t] = bpb[t];
  __syncthreads();
  const int n = blockIdx.y;
  const int m = blockIdx.x * 256 + t;
  const float4* src = (const float4*)(pair + ((size_t)n * 1024 + m) * 64);
  float acc[12];
#pragma unroll
  for (int h = 0; h < 12; ++h) acc[h] = bb[h];
#pragma unroll
  for (int j = 0; j < 16; ++j) {
    float4 p = src[j];
    const float* wj = wsh + j * 48;
#pragma unroll
    for (int h = 0; h < 12; ++h)
      acc[h] += p.x * wj[h] + p.y * wj[12 + h] + p.z * wj[24 + h] + p.w * wj[36 + h];
  }
#pragma unroll
  for (int h = 0; h < 12; ++h)
    pb[((size_t)h << 20) + (size_t)n * 1024 + m] = f2bf(acc[h]);
}

// ---------------------------------------------------------------------------
// attention: per (64-query tile, 256-key chunk, head): softmax(L) then
// MFMA AV into per-chunk accumulator slabs. Ls is XOR-swizzled (kc^(row&7)).
// ---------------------------------------------------------------------------
__global__ __launch_bounds__(256) void attn_k(
    const unsigned short* __restrict__ L, const unsigned short* __restrict__ VcatT,
    float* __restrict__ acc4)
{
  __shared__ unsigned short Ls[64 * 256];
  const int t = threadIdx.x, w = t >> 6, lane = t & 63;
  const int lr = lane & 15, lc = lane >> 4;
  const int n0 = blockIdx.x * 64;
  const int m0 = blockIdx.y * 256;
  const int h = blockIdx.z;

  const unsigned short* Lg = L + ((size_t)h * NTOK + n0) * 1024 + m0;
  for (int s = t; s < 2048; s += 256) {
    int row = s >> 5, kc = s & 31;
    u32x4 v = *(const u32x4*)(Lg + (size_t)row * 1024 + kc * 8);
    ((u32x4*)Ls)[row * 32 + (kc ^ (row & 7))] = v;
  }
  __syncthreads();

  for (int rr = 0; rr < 16; ++rr) {
    int row = w * 16 + rr;
    int slot = (lane >> 1) ^ (row & 7);
    unsigned short* ptr = Ls + row * 256 + slot * 8 + (lane & 1) * 4;
    ushort4 raw = *(const ushort4*)ptr;
    float v0 = bf2f(raw.x), v1 = bf2f(raw.y), v2 = bf2f(raw.z), v3 = bf2f(raw.w);
    float mx = fmaxf(fmaxf(v0, v1), fmaxf(v2, v3));
#pragma unroll
    for (int off = 32; off; off >>= 1) mx = fmaxf(mx, __shfl_xor(mx, off, 64));
    float e0 = __expf(v0 - mx), e1 = __expf(v1 - mx);
    float e2 = __expf(v2 - mx), e3 = __expf(v3 - mx);
    float sm = e0 + e1 + e2 + e3;
#pragma unroll
    for (int off = 32; off; off >>= 1) sm += __shfl_xor(sm, off, 64);
    float inv = 1.0f / sm;
    ushort4 pw;
    pw.x = f2bf(e0 * inv); pw.y = f2bf(e1 * inv);
    pw.z = f2bf(e2 * inv); pw.w = f2bf(e3 * inv);
    *(ushort4*)ptr = pw;
  }
  __syncthreads();

  f32x4 acc[5] = {};
  const unsigned short* Vg = VcatT + (size_t)h * 80 * NTOK + m0;
#pragma unroll
  for (int kk = 0; kk < 8; ++kk) {
    int row = w * 16 + lr;
    int kc = kk * 4 + lc;
    bf16x8 a = *(const bf16x8*)(Ls + row * 256 + (kc ^ (row & 7)) * 8);
#pragma unroll
    for (int nf = 0; nf < 5; ++nf) {
      int c = nf * 16 + lr;
      bf16x8 b = *(const bf16x8*)(Vg + (size_t)c * NTOK + kk * 32 + lc * 8);
      acc[nf] = __builtin_amdgcn_mfma_f32_16x16x32_bf16(a, b, acc[nf], 0, 0, 0);
    }
  }
  float* out = acc4 + ((size_t)blockIdx.y * NH + h) * NTOK * 80;
#pragma unroll
  for (int nf = 0; nf < 5; ++nf) {
#pragma unroll
    for (int r = 0; r < 4; ++r) {
      int nrow = n0 + w * 16 + lc * 4 + r;
      int c = nf * 16 + lr;
      out[(size_t)nrow * 80 + c] = acc[nf][r];
    }
  }
}

// ---------------------------------------------------------------------------
// reduce 4 chunk slabs -> ws (f32 [n][768]) and wp (bf16 [n][144])
// ---------------------------------------------------------------------------
__global__ __launch_bounds__(256) void reduce_out_k(
    const float* __restrict__ acc4, unsigned short* __restrict__ wp,
    float* __restrict__ wsum)
{
  int idx = blockIdx.x * 256 + threadIdx.x;
  if (idx >= 1024 * 912) return;
  int n = idx / 912, c = idx % 912;
  const size_t cs = (size_t)NH * NTOK * 80;
  if (c < 768) {
    int h = c >> 6, cc = c & 63;
    size_t base = ((size_t)h * NTOK + n) * 80 + cc;
    float v = acc4[base] + acc4[base + cs] + acc4[base + 2 * cs] + acc4[base + 3 * cs];
    wsum[(size_t)n * 768 + c] = v;
  } else {
    int c2 = c - 768;
    int h = c2 / 12, wo = c2 % 12;
    size_t base = ((size_t)h * NTOK + n) * 80 + 64 + wo;
    float v = acc4[base] + acc4[base + cs] + acc4[base + 2 * cs] + acc4[base + 3 * cs];
    wp[(size_t)n * 144 + c2] = f2bf(v);
  }
}

// ---------------------------------------------------------------------------
// layernorm(single + outpre) -> d_out
// ---------------------------------------------------------------------------
__global__ __launch_bounds__(256) void ln_k(
    const float* __restrict__ single, const float* __restrict__ outpre,
    const float* __restrict__ g, const float* __restrict__ b,
    float* __restrict__ out)
{
  const int row = blockIdx.x, t = threadIdx.x;
  __shared__ float red[8];
  size_t base = (size_t)row * 768;
  float x0 = single[base + t] + outpre[base + t];
  float x1 = single[base + t + 256] + outpre[base + t + 256];
  float x2 = single[base + t + 512] + outpre[base + t + 512];
  float s = x0 + x1 + x2;
#pragma unroll
  for (int off = 32; off; off >>= 1) s += __shfl_xor(s, off, 64);
  if ((t & 63) == 0) red[t >> 6] = s;
  __syncthreads();
  float mu = (red[0] + red[1] + red[2] + red[3]) * (1.0f / 768.0f);
  float d0 = x0 - mu, d1 = x1 - mu, d2 = x2 - mu;
  float vs = d0 * d0 + d1 * d1 + d2 * d2;
#pragma unroll
  for (int off = 32; off; off >>= 1) vs += __shfl_xor(vs, off, 64);
  if ((t & 63) == 0) red[4 + (t >> 6)] = vs;
  __syncthreads();
  float var = (red[4] + red[5] + red[6] + red[7]) * (1.0f / 768.0f);
  float rs = rsqrtf(var + 1e-5f);
  out[base + t]       = d0 * rs * g[t]       + b[t];
  out[base + t + 256] = d1 * rs * g[t + 256] + b[t + 256];
  out[base + t + 512] = d2 * rs * g[t + 512] + b[t + 512];
}

// ---------------------------------------------------------------------------
extern "C" void kernel_launch(void* const* d_in, const int* in_sizes, int n_in,
                              void* d_out, int out_size, void* d_ws, size_t ws_size,
                              hipStream_t stream)
{
  (void)in_sizes; (void)n_in; (void)out_size; (void)ws_size;
  const float* single = (const float*)d_in[0];
  const float* pair   = (const float*)d_in[1];
  const float* rot    = (const float*)d_in[2];
  const float* trans  = (const float*)d_in[3];
  const float* Wq  = (const float*)d_in[4];  const float* bq  = (const float*)d_in[5];
  const float* Wk  = (const float*)d_in[6];  const float* bk  = (const float*)d_in[7];
  const float* Wv  = (const float*)d_in[8];  const float* bv  = (const float*)d_in[9];
  const float* Wpb = (const float*)d_in[10]; const float* bpb = (const float*)d_in[11];
  const float* Wqp = (const float*)d_in[12]; const float* bqp = (const float*)d_in[13];
  const float* Wkp = (const float*)d_in[14]; const float* bkp = (const float*)d_in[15];
  const float* Wvp = (const float*)d_in[16]; const float* bvp = (const float*)d_in[17];
  const float* Wo  = (const float*)d_in[18]; const float* bo  = (const float*)d_in[19];
  const float* Wpo = (const float*)d_in[20]; const float* bpo = (const float*)d_in[21];
  const float* lng = (const float*)d_in[22]; const float* lnb = (const float*)d_in[23];

  char* ws = (char*)d_ws;
  unsigned short* sgl    = (unsigned short*)(ws + 0);
  unsigned short* wqkv   = (unsigned short*)(ws + 1572864);
  unsigned short* wpts   = (unsigned short*)(ws + 5111808);
  unsigned short* wpo_   = (unsigned short*)(ws + 5775360);
  unsigned short* wo_    = (unsigned short*)(ws + 5996544);
  float*          qkv    = (float*)(ws + 7176192);
  float*          praw   = (float*)(ws + 16613376);
  unsigned short* Acat   = (unsigned short*)(ws + 18382848);
  unsigned short* Bcat   = (unsigned short*)(ws + 20742144);
  unsigned short* VcatT  = (unsigned short*)(ws + 23101440);
  float*          q2k2   = (float*)(ws + 25067520);
  unsigned short* pbL    = (unsigned short*)(ws + 25165824);  // pair_bias -> logits (in place)
  float*          acc4   = (float*)(ws + 50331648);
  unsigned short* wp     = (unsigned short*)(ws + 66060288);
  float*          wsum   = (float*)(ws + 66355200);
  unsigned short* S      = (unsigned short*)(ws + 69500928);
  float*          outpre = (float*)(ws + 71073792);

  prep_k<<<14016, 256, 0, stream>>>(single, Wq, Wk, Wv, Wqp, Wkp, Wvp, Wpo, Wo,
                                    sgl, wqkv, wpts, wpo_, wo_);

  // q,k,v projections (one GEMM, N=2304)
  gemm_bt_k<0><<<dim3(8, 18, 1), 256, 0, stream>>>(
      sgl, 768, 0, wqkv, 768, 0, 2304, 768, 24,
      qkv, nullptr, 2304, 0, bq, bk, bv);

  // q_pts,k_pts,v_pts raw projections (N=432)
  gemm_bt_k<1><<<dim3(8, 4, 1), 256, 0, stream>>>(
      sgl, 768, 0, wpts, 768, 0, 432, 768, 24,
      praw, nullptr, 432, 0, bqp, bkp, bvp);

  rotate_k<<<1024, 256, 0, stream>>>(qkv, praw, rot, trans, Acat, Bcat, VcatT, q2k2);

  pairbias_k<<<dim3(4, 1024, 1), 256, 0, stream>>>(pair, Wpb, bpb, pbL);

  // logits = 0.125*(q.k + qp.kp) - 0.0625*(q2+k2) + pair_bias  (in-place bf16)
  gemm_bt_k<2><<<dim3(8, 8, 12), 256, 0, stream>>>(
      Acat, 96, 98304, Bcat, 96, 98304, 1024, 96, 3,
      nullptr, pbL, 1024, 1048576, q2k2, q2k2 + 12288, nullptr);

  attn_k<<<dim3(16, 4, 12), 256, 0, stream>>>(pbL, VcatT, acc4);

  reduce_out_k<<<3648, 256, 0, stream>>>(acc4, wp, wsum);

  // S = weighted_scalar + wp @ Wpo + bpo   (bf16)
  gemm_bt_k<3><<<dim3(8, 6, 1), 256, 0, stream>>>(
      wp, 144, 0, wpo_, 144, 0, 768, 144, 5,
      nullptr, S, 768, 0, bpo, wsum, nullptr);

  // outpre = S @ Wo + bo   (f32)
  gemm_bt_k<4><<<dim3(8, 6, 1), 256, 0, stream>>>(
      S, 768, 0, wo_, 768, 0, 768, 768, 24,
      outpre, nullptr, 768, 0, bo, nullptr, nullptr);

  ln_k<<<1024, 256, 0, stream>>>(single, outpre, lng, lnb, (float*)d_out);
}

// Round 2
// 196.033 us; speedup vs baseline: 1.4508x; 1.4508x over previous
//
#include <hip/hip_runtime.h>
#include <stdint.h>

#define NTOK 1024
#define NH 12

typedef short bf16x8 __attribute__((ext_vector_type(8)));
typedef float f32x4 __attribute__((ext_vector_type(4)));
typedef uint32_t u32x4 __attribute__((ext_vector_type(4)));

__device__ __forceinline__ unsigned short f2bf(float f) {
  union { float f; uint32_t u; } x; x.f = f;
  uint32_t r = x.u + 0x7FFFu + ((x.u >> 16) & 1u);
  return (unsigned short)(r >> 16);
}
__device__ __forceinline__ float bf2f(unsigned short u) {
  union { uint32_t u; float f; } x; x.u = ((uint32_t)u) << 16;
  return x.f;
}
__device__ __forceinline__ bf16x8 pack8(float4 a, float4 b) {
  bf16x8 r;
  r[0] = (short)f2bf(a.x); r[1] = (short)f2bf(a.y);
  r[2] = (short)f2bf(a.z); r[3] = (short)f2bf(a.w);
  r[4] = (short)f2bf(b.x); r[5] = (short)f2bf(b.y);
  r[6] = (short)f2bf(b.z); r[7] = (short)f2bf(b.w);
  return r;
}

// ---------------------------------------------------------------------------
// prep: single->bf16; weights -> transposed bf16 [n][k]; bias concat; WpbT16
// ---------------------------------------------------------------------------
__global__ __launch_bounds__(256) void prep_k(
    const float* __restrict__ single, const float* __restrict__ Wq,
    const float* __restrict__ Wk, const float* __restrict__ Wv,
    const float* __restrict__ Wqp, const float* __restrict__ Wkp,
    const float* __restrict__ Wvp, const float* __restrict__ Wpo,
    const float* __restrict__ Wo, const float* __restrict__ Wpb,
    const float* __restrict__ bq, const float* __restrict__ bk,
    const float* __restrict__ bv, const float* __restrict__ bqp,
    const float* __restrict__ bkp, const float* __restrict__ bvp,
    unsigned short* __restrict__ sgl, unsigned short* __restrict__ wcat,
    unsigned short* __restrict__ wpo, unsigned short* __restrict__ wo,
    float* __restrict__ bcat, unsigned short* __restrict__ wpbt)
{
  int idx = blockIdx.x * 256 + threadIdx.x;
  const int S0 = 786432;      // 1024*768
  const int SW = 589824;      // 768*768
  const int SP = 110592;      // 768*144
  if (idx < S0) { sgl[idx] = f2bf(single[idx]); return; }
  idx -= S0;
  if (idx < 3 * SW) {         // Wq|Wk|Wv -> wcat rows 0..2303
    int j = idx / SW, o = idx % SW;
    int n = o / 768, k = o % 768;
    const float* W = (j == 0) ? Wq : (j == 1) ? Wk : Wv;
    wcat[((size_t)(j * 768 + n)) * 768 + k] = f2bf(W[k * 768 + n]);
    return;
  }
  idx -= 3 * SW;
  if (idx < 3 * SP) {         // Wqp|Wkp|Wvp -> wcat rows 2304..2735
    int j = idx / SP, o = idx % SP;
    int n = o / 768, k = o % 768;
    const float* W = (j == 0) ? Wqp : (j == 1) ? Wkp : Wvp;
    wcat[((size_t)(2304 + j * 144 + n)) * 768 + k] = f2bf(W[k * 144 + n]);
    return;
  }
  idx -= 3 * SP;
  if (idx < SP) {             // Wpo (144x768) -> [768][144]
    int n = idx / 144, k = idx % 144;
    wpo[idx] = f2bf(Wpo[k * 768 + n]);
    return;
  }
  idx -= SP;
  if (idx < SW) {             // Wo -> [768][768]
    int n = idx / 768, k = idx % 768;
    wo[idx] = f2bf(Wo[k * 768 + n]);
    return;
  }
  idx -= SW;
  if (idx < 2736) {
    float v;
    if (idx < 768) v = bq[idx];
    else if (idx < 1536) v = bk[idx - 768];
    else if (idx < 2304) v = bv[idx - 1536];
    else if (idx < 2448) v = bqp[idx - 2304];
    else if (idx < 2592) v = bkp[idx - 2448];
    else v = bvp[idx - 2592];
    bcat[idx] = v;
    return;
  }
  idx -= 2736;
  if (idx < 1024) {           // WpbT16 [16][64]
    int h = idx >> 6, k = idx & 63;
    wpbt[idx] = (h < 12) ? f2bf(Wpb[k * 12 + h]) : (unsigned short)0;
    return;
  }
}

// ---------------------------------------------------------------------------
// bf16 MFMA GEMM, C = A(MxK) @ Bt(NxK)^T, 128x128 tile, BK=32, 4 waves.
// MODE 0: outf = v + p0[col]   MODE 3: outb = bf16(v + p0[col] + p1[row,col])
// ---------------------------------------------------------------------------
template <int MODE>
__global__ __launch_bounds__(256) void gemm_bt_k(
    const unsigned short* __restrict__ A, int lda,
    const unsigned short* __restrict__ Bt, int ldb,
    int Nact, int kmax, int ktiles,
    float* __restrict__ outf, unsigned short* __restrict__ outb, int ldc,
    const float* __restrict__ p0, const float* __restrict__ p1)
{
  __shared__ unsigned short As[128 * 32];
  __shared__ unsigned short Bs[128 * 32];
  const int t = threadIdx.x;
  const int w = t >> 6, lane = t & 63;
  const int wr = w >> 1, wc = w & 1;
  const int lr = lane & 15, lc = lane >> 4;
  const int m0 = blockIdx.x * 128, n0 = blockIdx.y * 128;

  const int s0 = t, s1 = t + 256;
  const int r0 = s0 >> 2, c0 = s0 & 3, r1 = s1 >> 2, c1 = s1 & 3;

  f32x4 acc[4][4] = {};
  u32x4 zz = {0u, 0u, 0u, 0u};
  u32x4 pa0, pa1, pq0, pq1;

#define LOAD_AB(KT)                                                              \
  do {                                                                           \
    int k0_ = (KT) * 32;                                                         \
    int g0_ = k0_ + c0 * 8, g1_ = k0_ + c1 * 8;                                  \
    pa0 = (g0_ < kmax) ? *(const u32x4*)(A + (size_t)(m0 + r0) * lda + g0_) : zz; \
    pa1 = (g1_ < kmax) ? *(const u32x4*)(A + (size_t)(m0 + r1) * lda + g1_) : zz; \
    pq0 = (g0_ < kmax && (n0 + r0) < Nact)                                       \
              ? *(const u32x4*)(Bt + (size_t)(n0 + r0) * ldb + g0_) : zz;        \
    pq1 = (g1_ < kmax && (n0 + r1) < Nact)                                       \
              ? *(const u32x4*)(Bt + (size_t)(n0 + r1) * ldb + g1_) : zz;        \
  } while (0)

  LOAD_AB(0);
  for (int kt = 0; kt < ktiles; ++kt) {
    __syncthreads();
    ((u32x4*)As)[r0 * 4 + c0] = pa0;
    ((u32x4*)As)[r1 * 4 + c1] = pa1;
    ((u32x4*)Bs)[r0 * 4 + c0] = pq0;
    ((u32x4*)Bs)[r1 * 4 + c1] = pq1;
    __syncthreads();
    if (kt + 1 < ktiles) LOAD_AB(kt + 1);

    bf16x8 af[4], bfr[4];
#pragma unroll
    for (int mi = 0; mi < 4; ++mi) {
      int row = wr * 64 + mi * 16 + lr;
      af[mi] = *(const bf16x8*)(As + (row * 4 + lc) * 8);
    }
#pragma unroll
    for (int ni = 0; ni < 4; ++ni) {
      int row = wc * 64 + ni * 16 + lr;
      bfr[ni] = *(const bf16x8*)(Bs + (row * 4 + lc) * 8);
    }
#pragma unroll
    for (int mi = 0; mi < 4; ++mi)
#pragma unroll
      for (int ni = 0; ni < 4; ++ni)
        acc[mi][ni] = __builtin_amdgcn_mfma_f32_16x16x32_bf16(
            af[mi], bfr[ni], acc[mi][ni], 0, 0, 0);
  }
#undef LOAD_AB

#pragma unroll
  for (int mi = 0; mi < 4; ++mi) {
#pragma unroll
    for (int ni = 0; ni < 4; ++ni) {
#pragma unroll
      for (int r = 0; r < 4; ++r) {
        int row = m0 + wr * 64 + mi * 16 + lc * 4 + r;
        int col = n0 + wc * 64 + ni * 16 + lr;
        if (col < Nact) {
          float v = acc[mi][ni][r];
          if constexpr (MODE == 0) {
            outf[(size_t)row * ldc + col] = v + p0[col];
          } else {
            float sv = v + p0[col] + p1[(size_t)row * 768 + col];
            outb[(size_t)row * ldc + col] = f2bf(sv);
          }
        }
      }
    }
  }
}

// ---------------------------------------------------------------------------
// rotate: apply rot/trans; build Acat/Bcat [h][n][96]=[q|qpts_g|0], VcatT
// [h][80][n]=[v|vpts_g|0]^T, q2k2 [2][12][n].
// ---------------------------------------------------------------------------
__global__ __launch_bounds__(256) void rotate_k(
    const float* __restrict__ qp, const float* __restrict__ rot,
    const float* __restrict__ trans,
    unsigned short* __restrict__ Acat, unsigned short* __restrict__ Bcat,
    unsigned short* __restrict__ VcatT, float* __restrict__ q2k2)
{
  const int n = blockIdx.x, t = threadIdx.x;
  __shared__ float R[9], T[3], rg[432];
  if (t < 9) R[t] = rot[n * 9 + t];
  if (t >= 9 && t < 12) T[t - 9] = trans[n * 3 + (t - 9)];
  __syncthreads();
  for (int s = t; s < 432; s += 256) {
    int j = s / 144, r = s % 144;
    int h = r / 12, wo = r % 12;
    int e = wo % 3;
    size_t base = (size_t)n * 2736 + 2304 + j * 144 + (r - e);
    float d0 = qp[base + 0], d1 = qp[base + 1], d2 = qp[base + 2];
    float val = d0 * R[e] + d1 * R[3 + e] + d2 * R[6 + e] + T[e];
    rg[s] = val;
    unsigned short bv = f2bf(val);
    if (j == 0)      Acat[((size_t)h * NTOK + n) * 96 + 64 + wo] = bv;
    else if (j == 1) Bcat[((size_t)h * NTOK + n) * 96 + 64 + wo] = bv;
    else             VcatT[((size_t)h * 80 + 64 + wo) * NTOK + n] = bv;
  }
  __syncthreads();
  for (int s = t; s < 2304; s += 256) {
    int j = s / 768, c = s % 768;
    int h = c >> 6, cc = c & 63;
    unsigned short bv = f2bf(qp[(size_t)n * 2736 + s]);
    if (j == 0)      Acat[((size_t)h * NTOK + n) * 96 + cc] = bv;
    else if (j == 1) Bcat[((size_t)h * NTOK + n) * 96 + cc] = bv;
    else             VcatT[((size_t)h * 80 + cc) * NTOK + n] = bv;
  }
  if (t < 240) {
    int h = t / 20, ix = 76 + t % 20;
    Acat[((size_t)h * NTOK + n) * 96 + ix] = 0;
    Bcat[((size_t)h * NTOK + n) * 96 + ix] = 0;
  }
  if (t >= 240 && t < 288) {
    int s = t - 240;
    int h = s / 4, rr = 76 + s % 4;
    VcatT[((size_t)h * 80 + rr) * NTOK + n] = 0;
  }
  if (t < 24) {
    int j = t / 12, h = t % 12;
    float sum = 0.f;
#pragma unroll
    for (int wo = 0; wo < 12; ++wo) {
      float v = rg[j * 144 + h * 12 + wo];
      sum += v * v;
    }
    q2k2[(size_t)(j * NH + h) * NTOK + n] = sum;
  }
}

// ---------------------------------------------------------------------------
// pair_bias via MFMA: pb[h][nm] = bf16(pair[nm][:].Wpb[:,h] + bpb[h]
//                                      - 0.0625*(q2[h][n]+k2[h][m]))
// ---------------------------------------------------------------------------
__global__ __launch_bounds__(256) void pairbias_k(
    const float* __restrict__ pair, const unsigned short* __restrict__ wpbt,
    const float* __restrict__ bpb, const float* __restrict__ q2k2,
    unsigned short* __restrict__ pb)
{
  const int t = threadIdx.x, w = t >> 6, lane = t & 63;
  const int lr = lane & 15, g = lane >> 4;
  bf16x8 wf0 = *(const bf16x8*)(wpbt + lr * 64 + g * 8);
  bf16x8 wf1 = *(const bf16x8*)(wpbt + lr * 64 + 32 + g * 8);
  const float bias_h = (lr < 12) ? bpb[lr] : 0.f;
  const int wid = blockIdx.x * 4 + w;
#pragma unroll
  for (int it = 0; it < 4; ++it) {
    int tile = wid * 4 + it;            // 0..65535
    int nm0 = tile * 16;
    int n = nm0 >> 10;
    int m0_ = nm0 & 1023;
    const float* src = pair + (size_t)(nm0 + lr) * 64 + g * 8;
    float4 aA = *(const float4*)(src);
    float4 aB = *(const float4*)(src + 4);
    float4 aC = *(const float4*)(src + 32);
    float4 aD = *(const float4*)(src + 36);
    bf16x8 f0 = pack8(aA, aB);
    bf16x8 f1 = pack8(aC, aD);
    f32x4 c = {0.f, 0.f, 0.f, 0.f};
    c = __builtin_amdgcn_mfma_f32_16x16x32_bf16(f0, wf0, c, 0, 0, 0);
    c = __builtin_amdgcn_mfma_f32_16x16x32_bf16(f1, wf1, c, 0, 0, 0);
    if (lr < 12) {
      float q2v = q2k2[lr * 1024 + n];
      float4 k2v = *(const float4*)(q2k2 + (12 + lr) * 1024 + m0_ + g * 4);
      ushort4 o;
      o.x = f2bf(c[0] + bias_h - 0.0625f * (q2v + k2v.x));
      o.y = f2bf(c[1] + bias_h - 0.0625f * (q2v + k2v.y));
      o.z = f2bf(c[2] + bias_h - 0.0625f * (q2v + k2v.z));
      o.w = f2bf(c[3] + bias_h - 0.0625f * (q2v + k2v.w));
      *(ushort4*)(pb + ((size_t)lr << 20) + (size_t)nm0 + g * 4) = o;
    }
  }
}

// ---------------------------------------------------------------------------
// fused attention: per (64 q-rows, 256-key chunk, head):
//   S^T = K @ Q^T (MFMA, lane owns one n-row) ; logits = 0.125*S + pb(LDS);
//   lane-local softmax ; P -> LDS (in-place over pb) ; AV MFMA -> chunk slab.
// ---------------------------------------------------------------------------
__global__ __launch_bounds__(256) void attn_k(
    const unsigned short* __restrict__ pb, const unsigned short* __restrict__ Acat,
    const unsigned short* __restrict__ Bcat, const unsigned short* __restrict__ VcatT,
    float* __restrict__ acc4)
{
  __shared__ unsigned short Ls[64 * 256];    // 32 KB, 16B slots, slot^(row&7)
  __shared__ unsigned short Bs[128 * 104];   // 26.6 KB, half key tile, pad 96->104
  const int t = threadIdx.x, w = t >> 6, lane = t & 63;
  const int lr = lane & 15, lc = lane >> 4;
  const int n0 = blockIdx.x * 64;
  const int m0 = blockIdx.y * 256;
  const int h  = blockIdx.z;

  // stage pb tile (64x256 bf16) swizzled
  const unsigned short* Pg = pb + ((size_t)h << 20) + (size_t)n0 * 1024 + m0;
#pragma unroll
  for (int i = 0; i < 8; ++i) {
    int idx = i * 256 + t;
    int row = idx >> 5, sl = idx & 31;
    u32x4 v = *(const u32x4*)(Pg + (size_t)row * 1024 + sl * 8);
    ((u32x4*)Ls)[row * 32 + (sl ^ (row & 7))] = v;
  }
  // stage key half-tile rows 0..127
  const unsigned short* Kg = Bcat + ((size_t)h * 1024 + m0) * 96;
#pragma unroll
  for (int i = 0; i < 6; ++i) {
    int idx = i * 256 + t;               // 0..1535
    int row = idx / 12, c = idx % 12;
    u32x4 v = *(const u32x4*)(Kg + (size_t)row * 96 + c * 8);
    *(u32x4*)(Bs + row * 104 + c * 8) = v;
  }
  __syncthreads();

  bf16x8 qf[3];
  const unsigned short* Qg = Acat + ((size_t)h * 1024 + n0 + w * 16 + lr) * 96;
#pragma unroll
  for (int kk = 0; kk < 3; ++kk) qf[kk] = *(const bf16x8*)(Qg + kk * 32 + lc * 8);

  f32x4 sa[16];
#pragma unroll
  for (int ct = 0; ct < 16; ++ct) sa[ct] = (f32x4){0.f, 0.f, 0.f, 0.f};

#pragma unroll
  for (int ct = 0; ct < 8; ++ct)
#pragma unroll
    for (int kk = 0; kk < 3; ++kk) {
      bf16x8 kf = *(const bf16x8*)(Bs + (ct * 16 + lr) * 104 + kk * 32 + lc * 8);
      sa[ct] = __builtin_amdgcn_mfma_f32_16x16x32_bf16(kf, qf[kk], sa[ct], 0, 0, 0);
    }
  __syncthreads();
#pragma unroll
  for (int i = 0; i < 6; ++i) {          // stage rows 128..255
    int idx = i * 256 + t;
    int row = idx / 12, c = idx % 12;
    u32x4 v = *(const u32x4*)(Kg + (size_t)(128 + row) * 96 + c * 8);
    *(u32x4*)(Bs + row * 104 + c * 8) = v;
  }
  __syncthreads();
#pragma unroll
  for (int ct = 8; ct < 16; ++ct)
#pragma unroll
    for (int kk = 0; kk < 3; ++kk) {
      bf16x8 kf = *(const bf16x8*)(Bs + ((ct - 8) * 16 + lr) * 104 + kk * 32 + lc * 8);
      sa[ct] = __builtin_amdgcn_mfma_f32_16x16x32_bf16(kf, qf[kk], sa[ct], 0, 0, 0);
    }

  // lane holds: n-row = w*16 + lr ; m = ct*16 + lc*4 + r
  const int nrow = w * 16 + lr;
  float lg[16][4];
  float mx = -1e30f;
#pragma unroll
  for (int ct = 0; ct < 16; ++ct) {
    int sl = (ct * 2 + (lc >> 1)) ^ (nrow & 7);
    const unsigned short* p = Ls + nrow * 256 + sl * 8 + (lc & 1) * 4;
    ushort4 pv = *(const ushort4*)p;
    lg[ct][0] = 0.125f * sa[ct][0] + bf2f(pv.x);
    lg[ct][1] = 0.125f * sa[ct][1] + bf2f(pv.y);
    lg[ct][2] = 0.125f * sa[ct][2] + bf2f(pv.z);
    lg[ct][3] = 0.125f * sa[ct][3] + bf2f(pv.w);
    mx = fmaxf(mx, fmaxf(fmaxf(lg[ct][0], lg[ct][1]), fmaxf(lg[ct][2], lg[ct][3])));
  }
  mx = fmaxf(mx, __shfl_xor(mx, 16, 64));
  mx = fmaxf(mx, __shfl_xor(mx, 32, 64));
  float sm = 0.f;
#pragma unroll
  for (int ct = 0; ct < 16; ++ct)
#pragma unroll
    for (int r = 0; r < 4; ++r) { lg[ct][r] = __expf(lg[ct][r] - mx); sm += lg[ct][r]; }
  sm += __shfl_xor(sm, 16, 64);
  sm += __shfl_xor(sm, 32, 64);
  float inv = 1.0f / sm;
#pragma unroll
  for (int ct = 0; ct < 16; ++ct) {
    int sl = (ct * 2 + (lc >> 1)) ^ (nrow & 7);
    unsigned short* p = Ls + nrow * 256 + sl * 8 + (lc & 1) * 4;
    ushort4 pw;
    pw.x = f2bf(lg[ct][0] * inv); pw.y = f2bf(lg[ct][1] * inv);
    pw.z = f2bf(lg[ct][2] * inv); pw.w = f2bf(lg[ct][3] * inv);
    *(ushort4*)p = pw;
  }
  __syncthreads();

  // AV
  f32x4 acc[5];
#pragma unroll
  for (int nf = 0; nf < 5; ++nf) acc[nf] = (f32x4){0.f, 0.f, 0.f, 0.f};
  const unsigned short* Vg = VcatT + (size_t)h * 80 * NTOK + m0;
#pragma unroll
  for (int kk = 0; kk < 8; ++kk) {
    int row = w * 16 + lr;
    int sl = (kk * 4 + lc) ^ (row & 7);
    bf16x8 a = *(const bf16x8*)(Ls + row * 256 + sl * 8);
#pragma unroll
    for (int nf = 0; nf < 5; ++nf) {
      int c = nf * 16 + lr;
      bf16x8 b = *(const bf16x8*)(Vg + (size_t)c * NTOK + kk * 32 + lc * 8);
      acc[nf] = __builtin_amdgcn_mfma_f32_16x16x32_bf16(a, b, acc[nf], 0, 0, 0);
    }
  }
  float* out = acc4 + ((size_t)blockIdx.y * NH + h) * (size_t)NTOK * 80;
#pragma unroll
  for (int nf = 0; nf < 5; ++nf)
#pragma unroll
    for (int r = 0; r < 4; ++r) {
      int orow = n0 + w * 16 + lc * 4 + r;
      int c = nf * 16 + lr;
      out[(size_t)orow * 80 + c] = acc[nf][r];
    }
}

// ---------------------------------------------------------------------------
// reduce 4 chunk slabs -> wsum (f32 [n][768]) and wp (bf16 [n][144])
// ---------------------------------------------------------------------------
__global__ __launch_bounds__(256) void reduce_out_k(
    const float* __restrict__ acc4, unsigned short* __restrict__ wp,
    float* __restrict__ wsum)
{
  int idx = blockIdx.x * 256 + threadIdx.x;
  if (idx >= 1024 * 912) return;
  int n = idx / 912, c = idx % 912;
  const size_t cs = (size_t)NH * NTOK * 80;
  if (c < 768) {
    int h = c >> 6, cc = c & 63;
    size_t base = ((size_t)h * NTOK + n) * 80 + cc;
    float v = acc4[base] + acc4[base + cs] + acc4[base + 2 * cs] + acc4[base + 3 * cs];
    wsum[(size_t)n * 768 + c] = v;
  } else {
    int c2 = c - 768;
    int h = c2 / 12, wo = c2 % 12;
    size_t base = ((size_t)h * NTOK + n) * 80 + 64 + wo;
    float v = acc4[base] + acc4[base + cs] + acc4[base + 2 * cs] + acc4[base + 3 * cs];
    wp[(size_t)n * 144 + c2] = f2bf(v);
  }
}

// ---------------------------------------------------------------------------
// layernorm(single + outpre) -> d_out
// ---------------------------------------------------------------------------
__global__ __launch_bounds__(256) void ln_k(
    const float* __restrict__ single, const float* __restrict__ outpre,
    const float* __restrict__ g, const float* __restrict__ b,
    float* __restrict__ out)
{
  const int row = blockIdx.x, t = threadIdx.x;
  __shared__ float red[8];
  size_t base = (size_t)row * 768;
  float x0 = single[base + t] + outpre[base + t];
  float x1 = single[base + t + 256] + outpre[base + t + 256];
  float x2 = single[base + t + 512] + outpre[base + t + 512];
  float s = x0 + x1 + x2;
#pragma unroll
  for (int off = 32; off; off >>= 1) s += __shfl_xor(s, off, 64);
  if ((t & 63) == 0) red[t >> 6] = s;
  __syncthreads();
  float mu = (red[0] + red[1] + red[2] + red[3]) * (1.0f / 768.0f);
  float d0 = x0 - mu, d1 = x1 - mu, d2 = x2 - mu;
  float vs = d0 * d0 + d1 * d1 + d2 * d2;
#pragma unroll
  for (int off = 32; off; off >>= 1) vs += __shfl_xor(vs, off, 64);
  if ((t & 63) == 0) red[4 + (t >> 6)] = vs;
  __syncthreads();
  float var = (red[4] + red[5] + red[6] + red[7]) * (1.0f / 768.0f);
  float rs = rsqrtf(var + 1e-5f);
  out[base + t]       = d0 * rs * g[t]       + b[t];
  out[base + t + 256] = d1 * rs * g[t + 256] + b[t + 256];
  out[base + t + 512] = d2 * rs * g[t + 512] + b[t + 512];
}

// ---------------------------------------------------------------------------
extern "C" void kernel_launch(void* const* d_in, const int* in_sizes, int n_in,
                              void* d_out, int out_size, void* d_ws, size_t ws_size,
                              hipStream_t stream)
{
  (void)in_sizes; (void)n_in; (void)out_size; (void)ws_size;
  const float* single = (const float*)d_in[0];
  const float* pair   = (const float*)d_in[1];
  const float* rot    = (const float*)d_in[2];
  const float* trans  = (const float*)d_in[3];
  const float* Wq  = (const float*)d_in[4];  const float* bq  = (const float*)d_in[5];
  const float* Wk  = (const float*)d_in[6];  const float* bk  = (const float*)d_in[7];
  const float* Wv  = (const float*)d_in[8];  const float* bv  = (const float*)d_in[9];
  const float* Wpb = (const float*)d_in[10]; const float* bpb = (const float*)d_in[11];
  const float* Wqp = (const float*)d_in[12]; const float* bqp = (const float*)d_in[13];
  const float* Wkp = (const float*)d_in[14]; const float* bkp = (const float*)d_in[15];
  const float* Wvp = (const float*)d_in[16]; const float* bvp = (const float*)d_in[17];
  const float* Wo  = (const float*)d_in[18]; const float* bo  = (const float*)d_in[19];
  const float* Wpo = (const float*)d_in[20]; const float* bpo = (const float*)d_in[21];
  const float* lng = (const float*)d_in[22]; const float* lnb = (const float*)d_in[23];

  char* ws = (char*)d_ws;
  unsigned short* sgl    = (unsigned short*)(ws + 0);
  unsigned short* wcat   = (unsigned short*)(ws + 1572864);
  unsigned short* wpo_   = (unsigned short*)(ws + 5775360);
  unsigned short* wo_    = (unsigned short*)(ws + 5996544);
  float*          bcat   = (float*)(ws + 7176192);
  unsigned short* wpbt   = (unsigned short*)(ws + 7187136);
  float*          qp     = (float*)(ws + 7189504);
  unsigned short* Acat   = (unsigned short*)(ws + 18396160);
  unsigned short* Bcat   = (unsigned short*)(ws + 20755456);
  unsigned short* VcatT  = (unsigned short*)(ws + 23114752);
  float*          q2k2   = (float*)(ws + 25080832);
  unsigned short* pb     = (unsigned short*)(ws + 25179136);
  float*          acc4   = (float*)(ws + 50344960);
  unsigned short* wp     = (unsigned short*)(ws + 66073600);
  float*          wsum   = (float*)(ws + 66368512);
  unsigned short* S      = (unsigned short*)(ws + 69514240);
  float*          outpre = (float*)(ws + 71087104);

  prep_k<<<14031, 256, 0, stream>>>(single, Wq, Wk, Wv, Wqp, Wkp, Wvp, Wpo, Wo,
                                    Wpb, bq, bk, bv, bqp, bkp, bvp,
                                    sgl, wcat, wpo_, wo_, bcat, wpbt);

  // merged projections: [q|k|v|qp|kp|vp] = single @ Wcat^T + bcat  (N=2736)
  gemm_bt_k<0><<<dim3(8, 22, 1), 256, 0, stream>>>(
      sgl, 768, wcat, 768, 2736, 768, 24, qp, nullptr, 2736, bcat, nullptr);

  rotate_k<<<1024, 256, 0, stream>>>(qp, rot, trans, Acat, Bcat, VcatT, q2k2);

  pairbias_k<<<4096, 256, 0, stream>>>(pair, wpbt, bpb, q2k2, pb);

  attn_k<<<dim3(16, 4, 12), 256, 0, stream>>>(pb, Acat, Bcat, VcatT, acc4);

  reduce_out_k<<<3648, 256, 0, stream>>>(acc4, wp, wsum);

  // S = weighted_scalar + wp @ Wpo + bpo   (bf16)
  gemm_bt_k<3><<<dim3(8, 6, 1), 256, 0, stream>>>(
      wp, 144, wpo_, 144, 768, 144, 5, nullptr, S, 768, bpo, wsum);

  // outpre = S @ Wo + bo   (f32)
  gemm_bt_k<0><<<dim3(8, 6, 1), 256, 0, stream>>>(
      S, 768, wo_, 768, 768, 768, 24, outpre, nullptr, 768, bo, nullptr);

  ln_k<<<1024, 256, 0, stream>>>(single, outpre, lng, lnb, (float*)d_out);
}

// Round 3
// 169.207 us; speedup vs baseline: 1.6808x; 1.1585x over previous
//
#include <hip/hip_runtime.h>
#include <stdint.h>

#define NTOK 1024
#define NH 12
#define QPSLAB 2801664   // 1024*2736

typedef short bf16x8 __attribute__((ext_vector_type(8)));
typedef float f32x4 __attribute__((ext_vector_type(4)));
typedef uint32_t u32x4 __attribute__((ext_vector_type(4)));

__device__ __forceinline__ unsigned short f2bf(float f) {
  union { float f; uint32_t u; } x; x.f = f;
  uint32_t r = x.u + 0x7FFFu + ((x.u >> 16) & 1u);
  return (unsigned short)(r >> 16);
}
__device__ __forceinline__ float bf2f(unsigned short u) {
  union { uint32_t u; float f; } x; x.u = ((uint32_t)u) << 16;
  return x.f;
}
__device__ __forceinline__ bf16x8 pack8(float4 a, float4 b) {
  bf16x8 r;
  r[0] = (short)f2bf(a.x); r[1] = (short)f2bf(a.y);
  r[2] = (short)f2bf(a.z); r[3] = (short)f2bf(a.w);
  r[4] = (short)f2bf(b.x); r[5] = (short)f2bf(b.y);
  r[6] = (short)f2bf(b.z); r[7] = (short)f2bf(b.w);
  return r;
}

// ---------------------------------------------------------------------------
// prep: conversions.  sgl bf16; wcat [2736][768]; WB[:, :768]=Wo^T (ldb 912);
// wpoA [144][768]; bcat; wpbt [16][64].
// ---------------------------------------------------------------------------
__global__ __launch_bounds__(256) void prep_k(
    const float* __restrict__ single, const float* __restrict__ Wq,
    const float* __restrict__ Wk, const float* __restrict__ Wv,
    const float* __restrict__ Wqp, const float* __restrict__ Wkp,
    const float* __restrict__ Wvp, const float* __restrict__ Wpo,
    const float* __restrict__ Wo, const float* __restrict__ Wpb,
    const float* __restrict__ bq, const float* __restrict__ bk,
    const float* __restrict__ bv, const float* __restrict__ bqp,
    const float* __restrict__ bkp, const float* __restrict__ bvp,
    unsigned short* __restrict__ sgl, unsigned short* __restrict__ wcat,
    unsigned short* __restrict__ WB, unsigned short* __restrict__ wpoA,
    float* __restrict__ bcat, unsigned short* __restrict__ wpbt)
{
  int idx = blockIdx.x * 256 + threadIdx.x;
  const int S0 = 786432;      // 1024*768
  const int SW = 589824;      // 768*768
  const int SP = 110592;      // 768*144
  if (idx < S0) { sgl[idx] = f2bf(single[idx]); return; }
  idx -= S0;
  if (idx < 3 * SW) {         // Wq|Wk|Wv -> wcat rows 0..2303
    int j = idx / SW, o = idx % SW;
    int n = o / 768, k = o % 768;
    const float* W = (j == 0) ? Wq : (j == 1) ? Wk : Wv;
    wcat[((size_t)(j * 768 + n)) * 768 + k] = f2bf(W[k * 768 + n]);
    return;
  }
  idx -= 3 * SW;
  if (idx < 3 * SP) {         // Wqp|Wkp|Wvp -> wcat rows 2304..2735
    int j = idx / SP, o = idx % SP;
    int n = o / 768, k = o % 768;
    const float* W = (j == 0) ? Wqp : (j == 1) ? Wkp : Wvp;
    wcat[((size_t)(2304 + j * 144 + n)) * 768 + k] = f2bf(W[k * 144 + n]);
    return;
  }
  idx -= 3 * SP;
  if (idx < SW) {             // Wo^T -> WB[n][k], ldb 912
    int n = idx / 768, k = idx % 768;
    WB[(size_t)n * 912 + k] = f2bf(Wo[k * 768 + n]);
    return;
  }
  idx -= SW;
  if (idx < SP) {             // Wpo straight copy [144][768]
    wpoA[idx] = f2bf(Wpo[idx]);
    return;
  }
  idx -= SP;
  if (idx < 2736) {
    float v;
    if (idx < 768) v = bq[idx];
    else if (idx < 1536) v = bk[idx - 768];
    else if (idx < 2304) v = bv[idx - 1536];
    else if (idx < 2448) v = bqp[idx - 2304];
    else if (idx < 2592) v = bkp[idx - 2448];
    else v = bvp[idx - 2592];
    bcat[idx] = v;
    return;
  }
  idx -= 2736;
  if (idx < 1024) {           // WpbT16 [16][64]
    int h = idx >> 6, k = idx & 63;
    wpbt[idx] = (h < 12) ? f2bf(Wpb[k * 12 + h]) : (unsigned short)0;
    return;
  }
}

// ---------------------------------------------------------------------------
// shared MFMA GEMM body, C = A(MactxK) @ Bt(NactxK)^T, 128x128 tile, BK=32.
// EPI 0: outf[row*ldc+col] = v (+ p0[col] if addbias)
// EPI 1: outb[col*912 + 768 + row] = bf16(v)   (wfuse scatter)
// ---------------------------------------------------------------------------
template <int EPI>
__device__ __forceinline__ void gemm_dev(
    unsigned short* As, unsigned short* Bs,
    const unsigned short* __restrict__ A, int lda, int Mact,
    const unsigned short* __restrict__ Bt, int ldb, int Nact,
    int kt0, int ktn, int kmax,
    float* __restrict__ outf, unsigned short* __restrict__ outb, int ldc,
    const float* __restrict__ p0, int mb, int nb, int addbias)
{
  const int t = threadIdx.x;
  const int w = t >> 6, lane = t & 63;
  const int wr = w >> 1, wc = w & 1;
  const int lr = lane & 15, lc = lane >> 4;
  const int m0 = mb * 128, n0 = nb * 128;
  const int r0 = t >> 2, c0 = t & 3;
  const int r1 = r0 + 64;

  f32x4 acc[4][4] = {};
  u32x4 zz = {0u, 0u, 0u, 0u};
  u32x4 pa0, pa1, pq0, pq1;

#define LOAD_AB(KT)                                                              \
  do {                                                                           \
    int k0_ = (KT) * 32;                                                         \
    int g0_ = k0_ + c0 * 8;                                                      \
    pa0 = (g0_ < kmax && (m0 + r0) < Mact)                                       \
              ? *(const u32x4*)(A + (size_t)(m0 + r0) * lda + g0_) : zz;         \
    pa1 = (g0_ < kmax && (m0 + r1) < Mact)                                       \
              ? *(const u32x4*)(A + (size_t)(m0 + r1) * lda + g0_) : zz;         \
    pq0 = (g0_ < kmax && (n0 + r0) < Nact)                                       \
              ? *(const u32x4*)(Bt + (size_t)(n0 + r0) * ldb + g0_) : zz;        \
    pq1 = (g0_ < kmax && (n0 + r1) < Nact)                                       \
              ? *(const u32x4*)(Bt + (size_t)(n0 + r1) * ldb + g0_) : zz;        \
  } while (0)

  LOAD_AB(kt0);
  for (int kt = kt0; kt < kt0 + ktn; ++kt) {
    __syncthreads();
    ((u32x4*)As)[r0 * 4 + c0] = pa0;
    ((u32x4*)As)[r1 * 4 + c0] = pa1;
    ((u32x4*)Bs)[r0 * 4 + c0] = pq0;
    ((u32x4*)Bs)[r1 * 4 + c0] = pq1;
    __syncthreads();
    if (kt + 1 < kt0 + ktn) LOAD_AB(kt + 1);

    bf16x8 af[4], bfr[4];
#pragma unroll
    for (int mi = 0; mi < 4; ++mi) {
      int row = wr * 64 + mi * 16 + lr;
      af[mi] = *(const bf16x8*)(As + (row * 4 + lc) * 8);
    }
#pragma unroll
    for (int ni = 0; ni < 4; ++ni) {
      int row = wc * 64 + ni * 16 + lr;
      bfr[ni] = *(const bf16x8*)(Bs + (row * 4 + lc) * 8);
    }
#pragma unroll
    for (int mi = 0; mi < 4; ++mi)
#pragma unroll
      for (int ni = 0; ni < 4; ++ni)
        acc[mi][ni] = __builtin_amdgcn_mfma_f32_16x16x32_bf16(
            af[mi], bfr[ni], acc[mi][ni], 0, 0, 0);
  }
#undef LOAD_AB

#pragma unroll
  for (int mi = 0; mi < 4; ++mi) {
#pragma unroll
    for (int ni = 0; ni < 4; ++ni) {
#pragma unroll
      for (int r = 0; r < 4; ++r) {
        int row = m0 + wr * 64 + mi * 16 + lc * 4 + r;
        int col = n0 + wc * 64 + ni * 16 + lr;
        if (row < Mact && col < Nact) {
          float v = acc[mi][ni][r];
          if constexpr (EPI == 0) {
            outf[(size_t)row * ldc + col] = addbias ? (v + p0[col]) : v;
          } else {
            outb[(size_t)col * 912 + 768 + row] = f2bf(v);
          }
        }
      }
    }
  }
}

// ---------------------------------------------------------------------------
// fat kernel (launch 2): [0..11] wfuse  [12..14] bfused  [15..366] proj(ks2)
// [367..4462] pairbias (no q2k2)
// ---------------------------------------------------------------------------
__global__ __launch_bounds__(256) void fat_k(
    const unsigned short* __restrict__ sgl, const unsigned short* __restrict__ wcat,
    const float* __restrict__ bcat, float* __restrict__ qp2,
    const float* __restrict__ pair, const unsigned short* __restrict__ wpbt,
    const float* __restrict__ bpb, unsigned short* __restrict__ pb,
    const unsigned short* __restrict__ wpoA, unsigned short* __restrict__ WB,
    const float* __restrict__ bpo, const float* __restrict__ Wo,
    const float* __restrict__ bo, float* __restrict__ bfused)
{
  __shared__ unsigned short As[128 * 32];
  __shared__ unsigned short Bs[128 * 32];
  const int bid = blockIdx.x;
  const int t = threadIdx.x;

  if (bid < 12) {             // wfuse: Wfused = Wpo @ Wo -> WB[:,768:912]
    int mb = bid & 1, nb = bid >> 1;
    gemm_dev<1>(As, Bs, wpoA, 768, 144, WB, 912, 768, 0, 24, 768,
                nullptr, WB, 912, nullptr, mb, nb, 0);
    return;
  }
  if (bid < 15) {             // bfused[n] = bpo @ Wo + bo
    int n = (bid - 12) * 256 + t;
    float s = bo[n];
    for (int j = 0; j < 768; ++j) s += bpo[j] * Wo[(size_t)j * 768 + n];
    bfused[n] = s;
    return;
  }
  if (bid < 367) {            // proj, k-split 2
    int pbid = bid - 15;
    int zk = pbid / 176, rem = pbid % 176;
    int mb = rem & 7, nb = rem >> 3;
    gemm_dev<0>(As, Bs, sgl, 768, 1024, wcat, 768, 2736,
                zk * 12, 12, 768,
                qp2 + (size_t)zk * QPSLAB, nullptr, 2736, bcat, mb, nb, zk == 0);
    return;
  }
  // pairbias
  {
    const int w = t >> 6, lane = t & 63;
    const int lr = lane & 15, g = lane >> 4;
    bf16x8 wf0 = *(const bf16x8*)(wpbt + lr * 64 + g * 8);
    bf16x8 wf1 = *(const bf16x8*)(wpbt + lr * 64 + 32 + g * 8);
    const float bias_h = (lr < 12) ? bpb[lr] : 0.f;
    const int wid = (bid - 367) * 4 + w;
#pragma unroll
    for (int it = 0; it < 4; ++it) {
      int tile = wid * 4 + it;          // 0..65535
      int nm0 = tile * 16;
      const float* src = pair + (size_t)(nm0 + lr) * 64 + g * 8;
      float4 aA = *(const float4*)(src);
      float4 aB = *(const float4*)(src + 4);
      float4 aC = *(const float4*)(src + 32);
      float4 aD = *(const float4*)(src + 36);
      bf16x8 f0 = pack8(aA, aB);
      bf16x8 f1 = pack8(aC, aD);
      f32x4 c = {0.f, 0.f, 0.f, 0.f};
      c = __builtin_amdgcn_mfma_f32_16x16x32_bf16(f0, wf0, c, 0, 0, 0);
      c = __builtin_amdgcn_mfma_f32_16x16x32_bf16(f1, wf1, c, 0, 0, 0);
      if (lr < 12) {
        ushort4 o;
        o.x = f2bf(c[0] + bias_h);
        o.y = f2bf(c[1] + bias_h);
        o.z = f2bf(c[2] + bias_h);
        o.w = f2bf(c[3] + bias_h);
        *(ushort4*)(pb + ((size_t)lr << 20) + (size_t)nm0 + g * 4) = o;
      }
    }
  }
}

// ---------------------------------------------------------------------------
// rotate: sum 2 qp slabs; apply rot/trans; build Acat/Bcat [h][n][96],
// VcatT [h][80][n], q2k2 [2][12][n].
// ---------------------------------------------------------------------------
__global__ __launch_bounds__(256) void rotate_k(
    const float* __restrict__ qp2, const float* __restrict__ rot,
    const float* __restrict__ trans,
    unsigned short* __restrict__ Acat, unsigned short* __restrict__ Bcat,
    unsigned short* __restrict__ VcatT, float* __restrict__ q2k2)
{
  const int n = blockIdx.x, t = threadIdx.x;
  __shared__ float R[9], T[3], rg[432];
  if (t < 9) R[t] = rot[n * 9 + t];
  if (t >= 9 && t < 12) T[t - 9] = trans[n * 3 + (t - 9)];
  __syncthreads();
  for (int s = t; s < 432; s += 256) {
    int j = s / 144, r = s % 144;
    int h = r / 12, wo = r % 12;
    int e = wo % 3;
    size_t base = (size_t)n * 2736 + 2304 + j * 144 + (r - e);
    float d0 = qp2[base + 0] + qp2[base + 0 + QPSLAB];
    float d1 = qp2[base + 1] + qp2[base + 1 + QPSLAB];
    float d2 = qp2[base + 2] + qp2[base + 2 + QPSLAB];
    float val = d0 * R[e] + d1 * R[3 + e] + d2 * R[6 + e] + T[e];
    rg[s] = val;
    unsigned short bv = f2bf(val);
    if (j == 0)      Acat[((size_t)h * NTOK + n) * 96 + 64 + wo] = bv;
    else if (j == 1) Bcat[((size_t)h * NTOK + n) * 96 + 64 + wo] = bv;
    else             VcatT[((size_t)h * 80 + 64 + wo) * NTOK + n] = bv;
  }
  __syncthreads();
  for (int s = t; s < 2304; s += 256) {
    int j = s / 768, c = s % 768;
    int h = c >> 6, cc = c & 63;
    size_t ix = (size_t)n * 2736 + s;
    unsigned short bv = f2bf(qp2[ix] + qp2[ix + QPSLAB]);
    if (j == 0)      Acat[((size_t)h * NTOK + n) * 96 + cc] = bv;
    else if (j == 1) Bcat[((size_t)h * NTOK + n) * 96 + cc] = bv;
    else             VcatT[((size_t)h * 80 + cc) * NTOK + n] = bv;
  }
  if (t < 240) {
    int h = t / 20, ix = 76 + t % 20;
    Acat[((size_t)h * NTOK + n) * 96 + ix] = 0;
    Bcat[((size_t)h * NTOK + n) * 96 + ix] = 0;
  }
  if (t >= 240 && t < 288) {
    int s = t - 240;
    int h = s / 4, rr = 76 + s % 4;
    VcatT[((size_t)h * 80 + rr) * NTOK + n] = 0;
  }
  if (t < 24) {
    int j = t / 12, h = t % 12;
    float sum = 0.f;
#pragma unroll
    for (int wo = 0; wo < 12; ++wo) {
      float v = rg[j * 144 + h * 12 + wo];
      sum += v * v;
    }
    q2k2[(size_t)(j * NH + h) * NTOK + n] = sum;
  }
}

// ---------------------------------------------------------------------------
// fused attention (per 64 q-rows, 256-key chunk, head). logits epilogue now
// also applies -0.0625*(q2+k2).
// ---------------------------------------------------------------------------
__global__ __launch_bounds__(256) void attn_k(
    const unsigned short* __restrict__ pb, const unsigned short* __restrict__ Acat,
    const unsigned short* __restrict__ Bcat, const unsigned short* __restrict__ VcatT,
    const float* __restrict__ q2k2, float* __restrict__ acc4)
{
  __shared__ unsigned short Ls[64 * 256];
  __shared__ unsigned short Bs[128 * 104];
  const int t = threadIdx.x, w = t >> 6, lane = t & 63;
  const int lr = lane & 15, lc = lane >> 4;
  const int n0 = blockIdx.x * 64;
  const int m0 = blockIdx.y * 256;
  const int h  = blockIdx.z;

  const unsigned short* Pg = pb + ((size_t)h << 20) + (size_t)n0 * 1024 + m0;
#pragma unroll
  for (int i = 0; i < 8; ++i) {
    int idx = i * 256 + t;
    int row = idx >> 5, sl = idx & 31;
    u32x4 v = *(const u32x4*)(Pg + (size_t)row * 1024 + sl * 8);
    ((u32x4*)Ls)[row * 32 + (sl ^ (row & 7))] = v;
  }
  const unsigned short* Kg = Bcat + ((size_t)h * 1024 + m0) * 96;
#pragma unroll
  for (int i = 0; i < 6; ++i) {
    int idx = i * 256 + t;
    int row = idx / 12, c = idx % 12;
    u32x4 v = *(const u32x4*)(Kg + (size_t)row * 96 + c * 8);
    *(u32x4*)(Bs + row * 104 + c * 8) = v;
  }
  __syncthreads();

  bf16x8 qf[3];
  const unsigned short* Qg = Acat + ((size_t)h * 1024 + n0 + w * 16 + lr) * 96;
#pragma unroll
  for (int kk = 0; kk < 3; ++kk) qf[kk] = *(const bf16x8*)(Qg + kk * 32 + lc * 8);

  f32x4 sa[16];
#pragma unroll
  for (int ct = 0; ct < 16; ++ct) sa[ct] = (f32x4){0.f, 0.f, 0.f, 0.f};

#pragma unroll
  for (int ct = 0; ct < 8; ++ct)
#pragma unroll
    for (int kk = 0; kk < 3; ++kk) {
      bf16x8 kf = *(const bf16x8*)(Bs + (ct * 16 + lr) * 104 + kk * 32 + lc * 8);
      sa[ct] = __builtin_amdgcn_mfma_f32_16x16x32_bf16(kf, qf[kk], sa[ct], 0, 0, 0);
    }
  __syncthreads();
#pragma unroll
  for (int i = 0; i < 6; ++i) {
    int idx = i * 256 + t;
    int row = idx / 12, c = idx % 12;
    u32x4 v = *(const u32x4*)(Kg + (size_t)(128 + row) * 96 + c * 8);
    *(u32x4*)(Bs + row * 104 + c * 8) = v;
  }
  __syncthreads();
#pragma unroll
  for (int ct = 8; ct < 16; ++ct)
#pragma unroll
    for (int kk = 0; kk < 3; ++kk) {
      bf16x8 kf = *(const bf16x8*)(Bs + ((ct - 8) * 16 + lr) * 104 + kk * 32 + lc * 8);
      sa[ct] = __builtin_amdgcn_mfma_f32_16x16x32_bf16(kf, qf[kk], sa[ct], 0, 0, 0);
    }

  const int nrow = w * 16 + lr;
  const float q2v = q2k2[(size_t)h * 1024 + n0 + nrow];
  const float* k2b = q2k2 + 12288 + (size_t)h * 1024 + m0;
  float lg[16][4];
  float mx = -1e30f;
#pragma unroll
  for (int ct = 0; ct < 16; ++ct) {
    int sl = (ct * 2 + (lc >> 1)) ^ (nrow & 7);
    const unsigned short* p = Ls + nrow * 256 + sl * 8 + (lc & 1) * 4;
    ushort4 pv = *(const ushort4*)p;
    float4 k2v = *(const float4*)(k2b + ct * 16 + lc * 4);
    lg[ct][0] = 0.125f * sa[ct][0] + bf2f(pv.x) - 0.0625f * (q2v + k2v.x);
    lg[ct][1] = 0.125f * sa[ct][1] + bf2f(pv.y) - 0.0625f * (q2v + k2v.y);
    lg[ct][2] = 0.125f * sa[ct][2] + bf2f(pv.z) - 0.0625f * (q2v + k2v.z);
    lg[ct][3] = 0.125f * sa[ct][3] + bf2f(pv.w) - 0.0625f * (q2v + k2v.w);
    mx = fmaxf(mx, fmaxf(fmaxf(lg[ct][0], lg[ct][1]), fmaxf(lg[ct][2], lg[ct][3])));
  }
  mx = fmaxf(mx, __shfl_xor(mx, 16, 64));
  mx = fmaxf(mx, __shfl_xor(mx, 32, 64));
  float sm = 0.f;
#pragma unroll
  for (int ct = 0; ct < 16; ++ct)
#pragma unroll
    for (int r = 0; r < 4; ++r) { lg[ct][r] = __expf(lg[ct][r] - mx); sm += lg[ct][r]; }
  sm += __shfl_xor(sm, 16, 64);
  sm += __shfl_xor(sm, 32, 64);
  float inv = 1.0f / sm;
#pragma unroll
  for (int ct = 0; ct < 16; ++ct) {
    int sl = (ct * 2 + (lc >> 1)) ^ (nrow & 7);
    unsigned short* p = Ls + nrow * 256 + sl * 8 + (lc & 1) * 4;
    ushort4 pw;
    pw.x = f2bf(lg[ct][0] * inv); pw.y = f2bf(lg[ct][1] * inv);
    pw.z = f2bf(lg[ct][2] * inv); pw.w = f2bf(lg[ct][3] * inv);
    *(ushort4*)p = pw;
  }
  __syncthreads();

  f32x4 acc[5];
#pragma unroll
  for (int nf = 0; nf < 5; ++nf) acc[nf] = (f32x4){0.f, 0.f, 0.f, 0.f};
  const unsigned short* Vg = VcatT + (size_t)h * 80 * NTOK + m0;
#pragma unroll
  for (int kk = 0; kk < 8; ++kk) {
    int row = w * 16 + lr;
    int sl = (kk * 4 + lc) ^ (row & 7);
    bf16x8 a = *(const bf16x8*)(Ls + row * 256 + sl * 8);
#pragma unroll
    for (int nf = 0; nf < 5; ++nf) {
      int c = nf * 16 + lr;
      bf16x8 b = *(const bf16x8*)(Vg + (size_t)c * NTOK + kk * 32 + lc * 8);
      acc[nf] = __builtin_amdgcn_mfma_f32_16x16x32_bf16(a, b, acc[nf], 0, 0, 0);
    }
  }
  float* out = acc4 + ((size_t)blockIdx.y * NH + h) * (size_t)NTOK * 80;
#pragma unroll
  for (int nf = 0; nf < 5; ++nf)
#pragma unroll
    for (int r = 0; r < 4; ++r) {
      int orow = n0 + w * 16 + lc * 4 + r;
      int c = nf * 16 + lr;
      out[(size_t)orow * 80 + c] = acc[nf][r];
    }
}

// ---------------------------------------------------------------------------
// reduce 4 chunk slabs -> AW bf16 [1024][912] = [ws | wp]
// ---------------------------------------------------------------------------
__global__ __launch_bounds__(256) void reduce_k(
    const float* __restrict__ acc4, unsigned short* __restrict__ AW)
{
  int idx = blockIdx.x * 256 + threadIdx.x;
  int n = idx / 912, c = idx % 912;
  const size_t cs = (size_t)NH * NTOK * 80;
  size_t base;
  if (c < 768) {
    int h = c >> 6, cc = c & 63;
    base = ((size_t)h * NTOK + n) * 80 + cc;
  } else {
    int c2 = c - 768;
    int h = c2 / 12, wo = c2 % 12;
    base = ((size_t)h * NTOK + n) * 80 + 64 + wo;
  }
  float v = acc4[base] + acc4[base + cs] + acc4[base + 2 * cs] + acc4[base + 3 * cs];
  AW[(size_t)n * 912 + c] = f2bf(v);
}

// ---------------------------------------------------------------------------
// tail gemm (k-split 4): outpre[z] = AW @ WB^T   (bias in ln)
// ---------------------------------------------------------------------------
__global__ __launch_bounds__(256) void tail_gemm_k(
    const unsigned short* __restrict__ AW, const unsigned short* __restrict__ WB,
    float* __restrict__ outpre)
{
  __shared__ unsigned short As[128 * 32];
  __shared__ unsigned short Bs[128 * 32];
  int z = blockIdx.z;
  int kt0 = z * 8, ktn = (z < 3) ? 8 : 5;
  gemm_dev<0>(As, Bs, AW, 912, 1024, WB, 912, 768, kt0, ktn, 912,
              outpre + (size_t)z * 786432, nullptr, 768, nullptr,
              blockIdx.x, blockIdx.y, 0);
}

// ---------------------------------------------------------------------------
// layernorm(single + sum(outpre slabs) + bfused) -> d_out
// ---------------------------------------------------------------------------
__global__ __launch_bounds__(256) void ln_k(
    const float* __restrict__ single, const float* __restrict__ outpre,
    const float* __restrict__ bfused, const float* __restrict__ g,
    const float* __restrict__ b, float* __restrict__ out)
{
  const int row = blockIdx.x, t = threadIdx.x;
  __shared__ float red[8];
  size_t base = (size_t)row * 768;
  const size_t SL = 786432;
  float x0 = single[base + t] + bfused[t]
           + outpre[base + t] + outpre[base + t + SL]
           + outpre[base + t + 2 * SL] + outpre[base + t + 3 * SL];
  float x1 = single[base + t + 256] + bfused[t + 256]
           + outpre[base + t + 256] + outpre[base + t + 256 + SL]
           + outpre[base + t + 256 + 2 * SL] + outpre[base + t + 256 + 3 * SL];
  float x2 = single[base + t + 512] + bfused[t + 512]
           + outpre[base + t + 512] + outpre[base + t + 512 + SL]
           + outpre[base + t + 512 + 2 * SL] + outpre[base + t + 512 + 3 * SL];
  float s = x0 + x1 + x2;
#pragma unroll
  for (int off = 32; off; off >>= 1) s += __shfl_xor(s, off, 64);
  if ((t & 63) == 0) red[t >> 6] = s;
  __syncthreads();
  float mu = (red[0] + red[1] + red[2] + red[3]) * (1.0f / 768.0f);
  float d0 = x0 - mu, d1 = x1 - mu, d2 = x2 - mu;
  float vs = d0 * d0 + d1 * d1 + d2 * d2;
#pragma unroll
  for (int off = 32; off; off >>= 1) vs += __shfl_xor(vs, off, 64);
  if ((t & 63) == 0) red[4 + (t >> 6)] = vs;
  __syncthreads();
  float var = (red[4] + red[5] + red[6] + red[7]) * (1.0f / 768.0f);
  float rs = rsqrtf(var + 1e-5f);
  out[base + t]       = d0 * rs * g[t]       + b[t];
  out[base + t + 256] = d1 * rs * g[t + 256] + b[t + 256];
  out[base + t + 512] = d2 * rs * g[t + 512] + b[t + 512];
}

// ---------------------------------------------------------------------------
extern "C" void kernel_launch(void* const* d_in, const int* in_sizes, int n_in,
                              void* d_out, int out_size, void* d_ws, size_t ws_size,
                              hipStream_t stream)
{
  (void)in_sizes; (void)n_in; (void)out_size; (void)ws_size;
  const float* single = (const float*)d_in[0];
  const float* pair   = (const float*)d_in[1];
  const float* rot    = (const float*)d_in[2];
  const float* trans  = (const float*)d_in[3];
  const float* Wq  = (const float*)d_in[4];  const float* bq  = (const float*)d_in[5];
  const float* Wk  = (const float*)d_in[6];  const float* bk  = (const float*)d_in[7];
  const float* Wv  = (const float*)d_in[8];  const float* bv  = (const float*)d_in[9];
  const float* Wpb = (const float*)d_in[10]; const float* bpb = (const float*)d_in[11];
  const float* Wqp = (const float*)d_in[12]; const float* bqp = (const float*)d_in[13];
  const float* Wkp = (const float*)d_in[14]; const float* bkp = (const float*)d_in[15];
  const float* Wvp = (const float*)d_in[16]; const float* bvp = (const float*)d_in[17];
  const float* Wo  = (const float*)d_in[18]; const float* bo  = (const float*)d_in[19];
  const float* Wpo = (const float*)d_in[20]; const float* bpo = (const float*)d_in[21];
  const float* lng = (const float*)d_in[22]; const float* lnb = (const float*)d_in[23];

  char* ws = (char*)d_ws;
  unsigned short* sgl    = (unsigned short*)(ws + 0);
  unsigned short* wcat   = (unsigned short*)(ws + 1572864);
  unsigned short* wpoA   = (unsigned short*)(ws + 5775360);
  unsigned short* WB     = (unsigned short*)(ws + 5996544);
  float*          bcat   = (float*)(ws + 7397376);
  unsigned short* wpbt   = (unsigned short*)(ws + 7408384);
  float*          bfused = (float*)(ws + 7410432);
  float*          qp2    = (float*)(ws + 7413504);
  unsigned short* Acat   = (unsigned short*)(ws + 29826816);
  unsigned short* Bcat   = (unsigned short*)(ws + 32186112);
  unsigned short* VcatT  = (unsigned short*)(ws + 34545408);
  float*          q2k2   = (float*)(ws + 36511488);
  unsigned short* pb     = (unsigned short*)(ws + 36609792);
  float*          acc4   = (float*)(ws + 61775616);
  unsigned short* AW     = (unsigned short*)(ws + 77504256);
  float*          outpre = (float*)(ws + 79372032);

  prep_k<<<14031, 256, 0, stream>>>(single, Wq, Wk, Wv, Wqp, Wkp, Wvp, Wpo, Wo,
                                    Wpb, bq, bk, bv, bqp, bkp, bvp,
                                    sgl, wcat, WB, wpoA, bcat, wpbt);

  fat_k<<<4463, 256, 0, stream>>>(sgl, wcat, bcat, qp2, pair, wpbt, bpb, pb,
                                  wpoA, WB, bpo, Wo, bo, bfused);

  rotate_k<<<1024, 256, 0, stream>>>(qp2, rot, trans, Acat, Bcat, VcatT, q2k2);

  attn_k<<<dim3(16, 4, 12), 256, 0, stream>>>(pb, Acat, Bcat, VcatT, q2k2, acc4);

  reduce_k<<<3648, 256, 0, stream>>>(acc4, AW);

  tail_gemm_k<<<dim3(8, 6, 4), 256, 0, stream>>>(AW, WB, outpre);

  ln_k<<<1024, 256, 0, stream>>>(single, outpre, bfused, lng, lnb, (float*)d_out);
}

// Round 4
// 159.813 us; speedup vs baseline: 1.7796x; 1.0588x over previous
//
#include <hip/hip_runtime.h>
#include <stdint.h>

#define NTOK 1024
#define NH 12
#define QPSLAB 2801664   // 1024*2736

typedef short bf16x8 __attribute__((ext_vector_type(8)));
typedef float f32x4 __attribute__((ext_vector_type(4)));
typedef uint32_t u32x4 __attribute__((ext_vector_type(4)));

__device__ __forceinline__ unsigned short f2bf(float f) {
  union { float f; uint32_t u; } x; x.f = f;
  uint32_t r = x.u + 0x7FFFu + ((x.u >> 16) & 1u);
  return (unsigned short)(r >> 16);
}
__device__ __forceinline__ float bf2f(unsigned short u) {
  union { uint32_t u; float f; } x; x.u = ((uint32_t)u) << 16;
  return x.f;
}
__device__ __forceinline__ bf16x8 pack8(float4 a, float4 b) {
  bf16x8 r;
  r[0] = (short)f2bf(a.x); r[1] = (short)f2bf(a.y);
  r[2] = (short)f2bf(a.z); r[3] = (short)f2bf(a.w);
  r[4] = (short)f2bf(b.x); r[5] = (short)f2bf(b.y);
  r[6] = (short)f2bf(b.z); r[7] = (short)f2bf(b.w);
  return r;
}

// ---------------------------------------------------------------------------
// prep: LDS-tiled transposes (coalesced both sides) + vectorized copies.
// blocks [0,2628): 64k x 16n transpose tiles
//   [0,1728): Wq|Wk|Wv -> wcat rows 0..2303
//   [1728,2052): Wqp|Wkp|Wvp -> wcat rows 2304..2735
//   [2052,2628): Wo -> WB[n][912] cols 0..767
// [2628,3396): sgl float4 copy; [3396,3504): wpoA copy;
// [3504,3515): bcat; [3515,3519): wpbt
// ---------------------------------------------------------------------------
__global__ __launch_bounds__(256) void prep_k(
    const float* __restrict__ single, const float* __restrict__ Wq,
    const float* __restrict__ Wk, const float* __restrict__ Wv,
    const float* __restrict__ Wqp, const float* __restrict__ Wkp,
    const float* __restrict__ Wvp, const float* __restrict__ Wpo,
    const float* __restrict__ Wo, const float* __restrict__ Wpb,
    const float* __restrict__ bq, const float* __restrict__ bk,
    const float* __restrict__ bv, const float* __restrict__ bqp,
    const float* __restrict__ bkp, const float* __restrict__ bvp,
    unsigned short* __restrict__ sgl, unsigned short* __restrict__ wcat,
    unsigned short* __restrict__ WB, unsigned short* __restrict__ wpoA,
    float* __restrict__ bcat, unsigned short* __restrict__ wpbt)
{
  const int bid = blockIdx.x, t = threadIdx.x;
  if (bid < 2628) {
    __shared__ unsigned short tl[16][72];
    int b = bid;
    const float* src; unsigned short* dst; int N, dstld, rowbase;
    if (b < 1728) {
      int j = b / 576; b -= j * 576;
      src = (j == 0) ? Wq : (j == 1) ? Wk : Wv;
      N = 768; dst = wcat; dstld = 768; rowbase = j * 768;
    } else if (b < 2052) {
      b -= 1728; int j = b / 108; b -= j * 108;
      src = (j == 0) ? Wqp : (j == 1) ? Wkp : Wvp;
      N = 144; dst = wcat; dstld = 768; rowbase = 2304 + j * 144;
    } else {
      b -= 2052; src = Wo; N = 768; dst = WB; dstld = 912; rowbase = 0;
    }
    const int k0 = (b % 12) * 64, n0 = (b / 12) * 16;
#pragma unroll
    for (int i = 0; i < 4; ++i) {
      int kk = (t >> 4) + i * 16;
      int nn = t & 15;
      tl[nn][kk] = f2bf(src[(size_t)(k0 + kk) * N + n0 + nn]);
    }
    __syncthreads();
#pragma unroll
    for (int i = 0; i < 4; ++i) {
      int kk = t & 63;
      int nn = (t >> 6) + i * 4;
      dst[(size_t)(rowbase + n0 + nn) * dstld + k0 + kk] = tl[nn][kk];
    }
    return;
  }
  if (bid < 3396) {           // sgl: 768 blocks, one float4 per thread
    int i = (bid - 2628) * 256 + t;
    float4 v = *(const float4*)(single + (size_t)i * 4);
    ushort4 o;
    o.x = f2bf(v.x); o.y = f2bf(v.y); o.z = f2bf(v.z); o.w = f2bf(v.w);
    *(ushort4*)(sgl + (size_t)i * 4) = o;
    return;
  }
  if (bid < 3504) {           // wpoA straight copy: 108 blocks x 4 elems
    int i = (bid - 3396) * 256 + t;
    float4 v = *(const float4*)(Wpo + (size_t)i * 4);
    ushort4 o;
    o.x = f2bf(v.x); o.y = f2bf(v.y); o.z = f2bf(v.z); o.w = f2bf(v.w);
    *(ushort4*)(wpoA + (size_t)i * 4) = o;
    return;
  }
  if (bid < 3515) {           // bcat
    int idx = (bid - 3504) * 256 + t;
    if (idx < 2736) {
      float v;
      if (idx < 768) v = bq[idx];
      else if (idx < 1536) v = bk[idx - 768];
      else if (idx < 2304) v = bv[idx - 1536];
      else if (idx < 2448) v = bqp[idx - 2304];
      else if (idx < 2592) v = bkp[idx - 2448];
      else v = bvp[idx - 2592];
      bcat[idx] = v;
    }
    return;
  }
  {                           // wpbt [16][64]
    int idx = (bid - 3515) * 256 + t;
    int h = idx >> 6, k = idx & 63;
    wpbt[idx] = (h < 12) ? f2bf(Wpb[k * 12 + h]) : (unsigned short)0;
  }
}

// ---------------------------------------------------------------------------
// shared MFMA GEMM body, C = A(MactxK) @ Bt(NactxK)^T, 128x128 tile, BK=32.
// EPI 0: outf[row*ldc+col] = v (+ p0[col] if addbias)
// EPI 1: outb[col*912 + 768 + row] = bf16(v)   (wfuse scatter)
// ---------------------------------------------------------------------------
template <int EPI>
__device__ __forceinline__ void gemm_dev(
    unsigned short* As, unsigned short* Bs,
    const unsigned short* __restrict__ A, int lda, int Mact,
    const unsigned short* __restrict__ Bt, int ldb, int Nact,
    int kt0, int ktn, int kmax,
    float* __restrict__ outf, unsigned short* __restrict__ outb, int ldc,
    const float* __restrict__ p0, int mb, int nb, int addbias)
{
  const int t = threadIdx.x;
  const int w = t >> 6, lane = t & 63;
  const int wr = w >> 1, wc = w & 1;
  const int lr = lane & 15, lc = lane >> 4;
  const int m0 = mb * 128, n0 = nb * 128;
  const int r0 = t >> 2, c0 = t & 3;
  const int r1 = r0 + 64;

  f32x4 acc[4][4] = {};
  u32x4 zz = {0u, 0u, 0u, 0u};
  u32x4 pa0, pa1, pq0, pq1;

#define LOAD_AB(KT)                                                              \
  do {                                                                           \
    int k0_ = (KT) * 32;                                                         \
    int g0_ = k0_ + c0 * 8;                                                      \
    pa0 = (g0_ < kmax && (m0 + r0) < Mact)                                       \
              ? *(const u32x4*)(A + (size_t)(m0 + r0) * lda + g0_) : zz;         \
    pa1 = (g0_ < kmax && (m0 + r1) < Mact)                                       \
              ? *(const u32x4*)(A + (size_t)(m0 + r1) * lda + g0_) : zz;         \
    pq0 = (g0_ < kmax && (n0 + r0) < Nact)                                       \
              ? *(const u32x4*)(Bt + (size_t)(n0 + r0) * ldb + g0_) : zz;        \
    pq1 = (g0_ < kmax && (n0 + r1) < Nact)                                       \
              ? *(const u32x4*)(Bt + (size_t)(n0 + r1) * ldb + g0_) : zz;        \
  } while (0)

  LOAD_AB(kt0);
  for (int kt = kt0; kt < kt0 + ktn; ++kt) {
    __syncthreads();
    ((u32x4*)As)[r0 * 4 + c0] = pa0;
    ((u32x4*)As)[r1 * 4 + c0] = pa1;
    ((u32x4*)Bs)[r0 * 4 + c0] = pq0;
    ((u32x4*)Bs)[r1 * 4 + c0] = pq1;
    __syncthreads();
    if (kt + 1 < kt0 + ktn) LOAD_AB(kt + 1);

    bf16x8 af[4], bfr[4];
#pragma unroll
    for (int mi = 0; mi < 4; ++mi) {
      int row = wr * 64 + mi * 16 + lr;
      af[mi] = *(const bf16x8*)(As + (row * 4 + lc) * 8);
    }
#pragma unroll
    for (int ni = 0; ni < 4; ++ni) {
      int row = wc * 64 + ni * 16 + lr;
      bfr[ni] = *(const bf16x8*)(Bs + (row * 4 + lc) * 8);
    }
#pragma unroll
    for (int mi = 0; mi < 4; ++mi)
#pragma unroll
      for (int ni = 0; ni < 4; ++ni)
        acc[mi][ni] = __builtin_amdgcn_mfma_f32_16x16x32_bf16(
            af[mi], bfr[ni], acc[mi][ni], 0, 0, 0);
  }
#undef LOAD_AB

#pragma unroll
  for (int mi = 0; mi < 4; ++mi) {
#pragma unroll
    for (int ni = 0; ni < 4; ++ni) {
#pragma unroll
      for (int r = 0; r < 4; ++r) {
        int row = m0 + wr * 64 + mi * 16 + lc * 4 + r;
        int col = n0 + wc * 64 + ni * 16 + lr;
        if (row < Mact && col < Nact) {
          float v = acc[mi][ni][r];
          if constexpr (EPI == 0) {
            outf[(size_t)row * ldc + col] = addbias ? (v + p0[col]) : v;
          } else {
            outb[(size_t)col * 912 + 768 + row] = f2bf(v);
          }
        }
      }
    }
  }
}

// ---------------------------------------------------------------------------
// fat kernel (launch 2): [0..11] wfuse  [12..14] bfused  [15..366] proj(ks2)
// [367..4462] pairbias
// ---------------------------------------------------------------------------
__global__ __launch_bounds__(256) void fat_k(
    const unsigned short* __restrict__ sgl, const unsigned short* __restrict__ wcat,
    const float* __restrict__ bcat, float* __restrict__ qp2,
    const float* __restrict__ pair, const unsigned short* __restrict__ wpbt,
    const float* __restrict__ bpb, unsigned short* __restrict__ pb,
    const unsigned short* __restrict__ wpoA, unsigned short* __restrict__ WB,
    const float* __restrict__ bpo, const float* __restrict__ Wo,
    const float* __restrict__ bo, float* __restrict__ bfused)
{
  __shared__ unsigned short As[128 * 32];
  __shared__ unsigned short Bs[128 * 32];
  const int bid = blockIdx.x;
  const int t = threadIdx.x;

  if (bid < 12) {             // wfuse: Wfused = Wpo @ Wo -> WB[:,768:912]
    int mb = bid & 1, nb = bid >> 1;
    gemm_dev<1>(As, Bs, wpoA, 768, 144, WB, 912, 768, 0, 24, 768,
                nullptr, WB, 912, nullptr, mb, nb, 0);
    return;
  }
  if (bid < 15) {             // bfused[n] = bpo @ Wo + bo
    int n = (bid - 12) * 256 + t;
    float s = bo[n];
    for (int j = 0; j < 768; ++j) s += bpo[j] * Wo[(size_t)j * 768 + n];
    bfused[n] = s;
    return;
  }
  if (bid < 367) {            // proj, k-split 2
    int pbid = bid - 15;
    int zk = pbid / 176, rem = pbid % 176;
    int mb = rem & 7, nb = rem >> 3;
    gemm_dev<0>(As, Bs, sgl, 768, 1024, wcat, 768, 2736,
                zk * 12, 12, 768,
                qp2 + (size_t)zk * QPSLAB, nullptr, 2736, bcat, mb, nb, zk == 0);
    return;
  }
  // pairbias
  {
    const int w = t >> 6, lane = t & 63;
    const int lr = lane & 15, g = lane >> 4;
    bf16x8 wf0 = *(const bf16x8*)(wpbt + lr * 64 + g * 8);
    bf16x8 wf1 = *(const bf16x8*)(wpbt + lr * 64 + 32 + g * 8);
    const float bias_h = (lr < 12) ? bpb[lr] : 0.f;
    const int wid = (bid - 367) * 4 + w;
#pragma unroll
    for (int it = 0; it < 4; ++it) {
      int tile = wid * 4 + it;          // 0..65535
      int nm0 = tile * 16;
      const float* src = pair + (size_t)(nm0 + lr) * 64 + g * 8;
      float4 aA = *(const float4*)(src);
      float4 aB = *(const float4*)(src + 4);
      float4 aC = *(const float4*)(src + 32);
      float4 aD = *(const float4*)(src + 36);
      bf16x8 f0 = pack8(aA, aB);
      bf16x8 f1 = pack8(aC, aD);
      f32x4 c = {0.f, 0.f, 0.f, 0.f};
      c = __builtin_amdgcn_mfma_f32_16x16x32_bf16(f0, wf0, c, 0, 0, 0);
      c = __builtin_amdgcn_mfma_f32_16x16x32_bf16(f1, wf1, c, 0, 0, 0);
      if (lr < 12) {
        ushort4 o;
        o.x = f2bf(c[0] + bias_h);
        o.y = f2bf(c[1] + bias_h);
        o.z = f2bf(c[2] + bias_h);
        o.w = f2bf(c[3] + bias_h);
        *(ushort4*)(pb + ((size_t)lr << 20) + (size_t)nm0 + g * 4) = o;
      }
    }
  }
}

// ---------------------------------------------------------------------------
// rotate: sum 2 qp slabs; apply rot/trans; build Acat/Bcat [h][n][96],
// VcatT [h][80][n], q2k2 [2][12][n].
// ---------------------------------------------------------------------------
__global__ __launch_bounds__(256) void rotate_k(
    const float* __restrict__ qp2, const float* __restrict__ rot,
    const float* __restrict__ trans,
    unsigned short* __restrict__ Acat, unsigned short* __restrict__ Bcat,
    unsigned short* __restrict__ VcatT, float* __restrict__ q2k2)
{
  const int n = blockIdx.x, t = threadIdx.x;
  __shared__ float R[9], T[3], rg[432];
  if (t < 9) R[t] = rot[n * 9 + t];
  if (t >= 9 && t < 12) T[t - 9] = trans[n * 3 + (t - 9)];
  __syncthreads();
  for (int s = t; s < 432; s += 256) {
    int j = s / 144, r = s % 144;
    int h = r / 12, wo = r % 12;
    int e = wo % 3;
    size_t base = (size_t)n * 2736 + 2304 + j * 144 + (r - e);
    float d0 = qp2[base + 0] + qp2[base + 0 + QPSLAB];
    float d1 = qp2[base + 1] + qp2[base + 1 + QPSLAB];
    float d2 = qp2[base + 2] + qp2[base + 2 + QPSLAB];
    float val = d0 * R[e] + d1 * R[3 + e] + d2 * R[6 + e] + T[e];
    rg[s] = val;
    unsigned short bv = f2bf(val);
    if (j == 0)      Acat[((size_t)h * NTOK + n) * 96 + 64 + wo] = bv;
    else if (j == 1) Bcat[((size_t)h * NTOK + n) * 96 + 64 + wo] = bv;
    else             VcatT[((size_t)h * 80 + 64 + wo) * NTOK + n] = bv;
  }
  __syncthreads();
  for (int s = t; s < 2304; s += 256) {
    int j = s / 768, c = s % 768;
    int h = c >> 6, cc = c & 63;
    size_t ix = (size_t)n * 2736 + s;
    unsigned short bv = f2bf(qp2[ix] + qp2[ix + QPSLAB]);
    if (j == 0)      Acat[((size_t)h * NTOK + n) * 96 + cc] = bv;
    else if (j == 1) Bcat[((size_t)h * NTOK + n) * 96 + cc] = bv;
    else             VcatT[((size_t)h * 80 + cc) * NTOK + n] = bv;
  }
  if (t < 240) {
    int h = t / 20, ix = 76 + t % 20;
    Acat[((size_t)h * NTOK + n) * 96 + ix] = 0;
    Bcat[((size_t)h * NTOK + n) * 96 + ix] = 0;
  }
  if (t >= 240 && t < 288) {
    int s = t - 240;
    int h = s / 4, rr = 76 + s % 4;
    VcatT[((size_t)h * 80 + rr) * NTOK + n] = 0;
  }
  if (t < 24) {
    int j = t / 12, h = t % 12;
    float sum = 0.f;
#pragma unroll
    for (int wo = 0; wo < 12; ++wo) {
      float v = rg[j * 144 + h * 12 + wo];
      sum += v * v;
    }
    q2k2[(size_t)(j * NH + h) * NTOK + n] = sum;
  }
}

// ---------------------------------------------------------------------------
// fused attention (per 64 q-rows, 256-key chunk, head); logits folded into
// sa in place (VGPR).
// ---------------------------------------------------------------------------
__global__ __launch_bounds__(256) void attn_k(
    const unsigned short* __restrict__ pb, const unsigned short* __restrict__ Acat,
    const unsigned short* __restrict__ Bcat, const unsigned short* __restrict__ VcatT,
    const float* __restrict__ q2k2, float* __restrict__ acc4)
{
  __shared__ unsigned short Ls[64 * 256];
  __shared__ unsigned short Bs[128 * 104];
  const int t = threadIdx.x, w = t >> 6, lane = t & 63;
  const int lr = lane & 15, lc = lane >> 4;
  const int n0 = blockIdx.x * 64;
  const int m0 = blockIdx.y * 256;
  const int h  = blockIdx.z;

  const unsigned short* Pg = pb + ((size_t)h << 20) + (size_t)n0 * 1024 + m0;
#pragma unroll
  for (int i = 0; i < 8; ++i) {
    int idx = i * 256 + t;
    int row = idx >> 5, sl = idx & 31;
    u32x4 v = *(const u32x4*)(Pg + (size_t)row * 1024 + sl * 8);
    ((u32x4*)Ls)[row * 32 + (sl ^ (row & 7))] = v;
  }
  const unsigned short* Kg = Bcat + ((size_t)h * 1024 + m0) * 96;
#pragma unroll
  for (int i = 0; i < 6; ++i) {
    int idx = i * 256 + t;
    int row = idx / 12, c = idx % 12;
    u32x4 v = *(const u32x4*)(Kg + (size_t)row * 96 + c * 8);
    *(u32x4*)(Bs + row * 104 + c * 8) = v;
  }
  __syncthreads();

  bf16x8 qf[3];
  const unsigned short* Qg = Acat + ((size_t)h * 1024 + n0 + w * 16 + lr) * 96;
#pragma unroll
  for (int kk = 0; kk < 3; ++kk) qf[kk] = *(const bf16x8*)(Qg + kk * 32 + lc * 8);

  f32x4 sa[16];
#pragma unroll
  for (int ct = 0; ct < 16; ++ct) sa[ct] = (f32x4){0.f, 0.f, 0.f, 0.f};

#pragma unroll
  for (int ct = 0; ct < 8; ++ct)
#pragma unroll
    for (int kk = 0; kk < 3; ++kk) {
      bf16x8 kf = *(const bf16x8*)(Bs + (ct * 16 + lr) * 104 + kk * 32 + lc * 8);
      sa[ct] = __builtin_amdgcn_mfma_f32_16x16x32_bf16(kf, qf[kk], sa[ct], 0, 0, 0);
    }
  __syncthreads();
#pragma unroll
  for (int i = 0; i < 6; ++i) {
    int idx = i * 256 + t;
    int row = idx / 12, c = idx % 12;
    u32x4 v = *(const u32x4*)(Kg + (size_t)(128 + row) * 96 + c * 8);
    *(u32x4*)(Bs + row * 104 + c * 8) = v;
  }
  __syncthreads();
#pragma unroll
  for (int ct = 8; ct < 16; ++ct)
#pragma unroll
    for (int kk = 0; kk < 3; ++kk) {
      bf16x8 kf = *(const bf16x8*)(Bs + ((ct - 8) * 16 + lr) * 104 + kk * 32 + lc * 8);
      sa[ct] = __builtin_amdgcn_mfma_f32_16x16x32_bf16(kf, qf[kk], sa[ct], 0, 0, 0);
    }

  const int nrow = w * 16 + lr;
  const float q2v = q2k2[(size_t)h * 1024 + n0 + nrow];
  const float* k2b = q2k2 + 12288 + (size_t)h * 1024 + m0;
  float mx = -1e30f;
#pragma unroll
  for (int ct = 0; ct < 16; ++ct) {
    int sl = (ct * 2 + (lc >> 1)) ^ (nrow & 7);
    const unsigned short* p = Ls + nrow * 256 + sl * 8 + (lc & 1) * 4;
    ushort4 pv = *(const ushort4*)p;
    float4 k2v = *(const float4*)(k2b + ct * 16 + lc * 4);
    sa[ct][0] = 0.125f * sa[ct][0] + bf2f(pv.x) - 0.0625f * (q2v + k2v.x);
    sa[ct][1] = 0.125f * sa[ct][1] + bf2f(pv.y) - 0.0625f * (q2v + k2v.y);
    sa[ct][2] = 0.125f * sa[ct][2] + bf2f(pv.z) - 0.0625f * (q2v + k2v.z);
    sa[ct][3] = 0.125f * sa[ct][3] + bf2f(pv.w) - 0.0625f * (q2v + k2v.w);
    mx = fmaxf(mx, fmaxf(fmaxf(sa[ct][0], sa[ct][1]), fmaxf(sa[ct][2], sa[ct][3])));
  }
  mx = fmaxf(mx, __shfl_xor(mx, 16, 64));
  mx = fmaxf(mx, __shfl_xor(mx, 32, 64));
  float sm = 0.f;
#pragma unroll
  for (int ct = 0; ct < 16; ++ct)
#pragma unroll
    for (int r = 0; r < 4; ++r) { sa[ct][r] = __expf(sa[ct][r] - mx); sm += sa[ct][r]; }
  sm += __shfl_xor(sm, 16, 64);
  sm += __shfl_xor(sm, 32, 64);
  float inv = 1.0f / sm;
#pragma unroll
  for (int ct = 0; ct < 16; ++ct) {
    int sl = (ct * 2 + (lc >> 1)) ^ (nrow & 7);
    unsigned short* p = Ls + nrow * 256 + sl * 8 + (lc & 1) * 4;
    ushort4 pw;
    pw.x = f2bf(sa[ct][0] * inv); pw.y = f2bf(sa[ct][1] * inv);
    pw.z = f2bf(sa[ct][2] * inv); pw.w = f2bf(sa[ct][3] * inv);
    *(ushort4*)p = pw;
  }
  __syncthreads();

  f32x4 acc[5];
#pragma unroll
  for (int nf = 0; nf < 5; ++nf) acc[nf] = (f32x4){0.f, 0.f, 0.f, 0.f};
  const unsigned short* Vg = VcatT + (size_t)h * 80 * NTOK + m0;
#pragma unroll
  for (int kk = 0; kk < 8; ++kk) {
    int row = w * 16 + lr;
    int sl = (kk * 4 + lc) ^ (row & 7);
    bf16x8 a = *(const bf16x8*)(Ls + row * 256 + sl * 8);
#pragma unroll
    for (int nf = 0; nf < 5; ++nf) {
      int c = nf * 16 + lr;
      bf16x8 b = *(const bf16x8*)(Vg + (size_t)c * NTOK + kk * 32 + lc * 8);
      acc[nf] = __builtin_amdgcn_mfma_f32_16x16x32_bf16(a, b, acc[nf], 0, 0, 0);
    }
  }
  float* out = acc4 + ((size_t)blockIdx.y * NH + h) * (size_t)NTOK * 80;
#pragma unroll
  for (int nf = 0; nf < 5; ++nf)
#pragma unroll
    for (int r = 0; r < 4; ++r) {
      int orow = n0 + w * 16 + lc * 4 + r;
      int c = nf * 16 + lr;
      out[(size_t)orow * 80 + c] = acc[nf][r];
    }
}

// ---------------------------------------------------------------------------
// reduce 4 chunk slabs -> AW bf16 [1024][912] = [ws | wp]
// ---------------------------------------------------------------------------
__global__ __launch_bounds__(256) void reduce_k(
    const float* __restrict__ acc4, unsigned short* __restrict__ AW)
{
  int idx = blockIdx.x * 256 + threadIdx.x;
  int n = idx / 912, c = idx % 912;
  const size_t cs = (size_t)NH * NTOK * 80;
  size_t base;
  if (c < 768) {
    int h = c >> 6, cc = c & 63;
    base = ((size_t)h * NTOK + n) * 80 + cc;
  } else {
    int c2 = c - 768;
    int h = c2 / 12, wo = c2 % 12;
    base = ((size_t)h * NTOK + n) * 80 + 64 + wo;
  }
  float v = acc4[base] + acc4[base + cs] + acc4[base + 2 * cs] + acc4[base + 3 * cs];
  AW[(size_t)n * 912 + c] = f2bf(v);
}

// ---------------------------------------------------------------------------
// tail gemm (k-split 4): outpre[z] = AW @ WB^T   (bias in ln)
// ---------------------------------------------------------------------------
__global__ __launch_bounds__(256) void tail_gemm_k(
    const unsigned short* __restrict__ AW, const unsigned short* __restrict__ WB,
    float* __restrict__ outpre)
{
  __shared__ unsigned short As[128 * 32];
  __shared__ unsigned short Bs[128 * 32];
  int z = blockIdx.z;
  int kt0 = z * 8, ktn = (z < 3) ? 8 : 5;
  gemm_dev<0>(As, Bs, AW, 912, 1024, WB, 912, 768, kt0, ktn, 912,
              outpre + (size_t)z * 786432, nullptr, 768, nullptr,
              blockIdx.x, blockIdx.y, 0);
}

// ---------------------------------------------------------------------------
// layernorm(single + sum(outpre slabs) + bfused) -> d_out
// ---------------------------------------------------------------------------
__global__ __launch_bounds__(256) void ln_k(
    const float* __restrict__ single, const float* __restrict__ outpre,
    const float* __restrict__ bfused, const float* __restrict__ g,
    const float* __restrict__ b, float* __restrict__ out)
{
  const int row = blockIdx.x, t = threadIdx.x;
  __shared__ float red[8];
  size_t base = (size_t)row * 768;
  const size_t SL = 786432;
  float x0 = single[base + t] + bfused[t]
           + outpre[base + t] + outpre[base + t + SL]
           + outpre[base + t + 2 * SL] + outpre[base + t + 3 * SL];
  float x1 = single[base + t + 256] + bfused[t + 256]
           + outpre[base + t + 256] + outpre[base + t + 256 + SL]
           + outpre[base + t + 256 + 2 * SL] + outpre[base + t + 256 + 3 * SL];
  float x2 = single[base + t + 512] + bfused[t + 512]
           + outpre[base + t + 512] + outpre[base + t + 512 + SL]
           + outpre[base + t + 512 + 2 * SL] + outpre[base + t + 512 + 3 * SL];
  float s = x0 + x1 + x2;
#pragma unroll
  for (int off = 32; off; off >>= 1) s += __shfl_xor(s, off, 64);
  if ((t & 63) == 0) red[t >> 6] = s;
  __syncthreads();
  float mu = (red[0] + red[1] + red[2] + red[3]) * (1.0f / 768.0f);
  float d0 = x0 - mu, d1 = x1 - mu, d2 = x2 - mu;
  float vs = d0 * d0 + d1 * d1 + d2 * d2;
#pragma unroll
  for (int off = 32; off; off >>= 1) vs += __shfl_xor(vs, off, 64);
  if ((t & 63) == 0) red[4 + (t >> 6)] = vs;
  __syncthreads();
  float var = (red[4] + red[5] + red[6] + red[7]) * (1.0f / 768.0f);
  float rs = rsqrtf(var + 1e-5f);
  out[base + t]       = d0 * rs * g[t]       + b[t];
  out[base + t + 256] = d1 * rs * g[t + 256] + b[t + 256];
  out[base + t + 512] = d2 * rs * g[t + 512] + b[t + 512];
}

// ---------------------------------------------------------------------------
extern "C" void kernel_launch(void* const* d_in, const int* in_sizes, int n_in,
                              void* d_out, int out_size, void* d_ws, size_t ws_size,
                              hipStream_t stream)
{
  (void)in_sizes; (void)n_in; (void)out_size; (void)ws_size;
  const float* single = (const float*)d_in[0];
  const float* pair   = (const float*)d_in[1];
  const float* rot    = (const float*)d_in[2];
  const float* trans  = (const float*)d_in[3];
  const float* Wq  = (const float*)d_in[4];  const float* bq  = (const float*)d_in[5];
  const float* Wk  = (const float*)d_in[6];  const float* bk  = (const float*)d_in[7];
  const float* Wv  = (const float*)d_in[8];  const float* bv  = (const float*)d_in[9];
  const float* Wpb = (const float*)d_in[10]; const float* bpb = (const float*)d_in[11];
  const float* Wqp = (const float*)d_in[12]; const float* bqp = (const float*)d_in[13];
  const float* Wkp = (const float*)d_in[14]; const float* bkp = (const float*)d_in[15];
  const float* Wvp = (const float*)d_in[16]; const float* bvp = (const float*)d_in[17];
  const float* Wo  = (const float*)d_in[18]; const float* bo  = (const float*)d_in[19];
  const float* Wpo = (const float*)d_in[20]; const float* bpo = (const float*)d_in[21];
  const float* lng = (const float*)d_in[22]; const float* lnb = (const float*)d_in[23];

  char* ws = (char*)d_ws;
  unsigned short* sgl    = (unsigned short*)(ws + 0);
  unsigned short* wcat   = (unsigned short*)(ws + 1572864);
  unsigned short* wpoA   = (unsigned short*)(ws + 5775360);
  unsigned short* WB     = (unsigned short*)(ws + 5996544);
  float*          bcat   = (float*)(ws + 7397376);
  unsigned short* wpbt   = (unsigned short*)(ws + 7408384);
  float*          bfused = (float*)(ws + 7410432);
  float*          qp2    = (float*)(ws + 7413504);
  unsigned short* Acat   = (unsigned short*)(ws + 29826816);
  unsigned short* Bcat   = (unsigned short*)(ws + 32186112);
  unsigned short* VcatT  = (unsigned short*)(ws + 34545408);
  float*          q2k2   = (float*)(ws + 36511488);
  unsigned short* pb     = (unsigned short*)(ws + 36609792);
  float*          acc4   = (float*)(ws + 61775616);
  unsigned short* AW     = (unsigned short*)(ws + 77504256);
  float*          outpre = (float*)(ws + 79372032);

  prep_k<<<3519, 256, 0, stream>>>(single, Wq, Wk, Wv, Wqp, Wkp, Wvp, Wpo, Wo,
                                   Wpb, bq, bk, bv, bqp, bkp, bvp,
                                   sgl, wcat, WB, wpoA, bcat, wpbt);

  fat_k<<<4463, 256, 0, stream>>>(sgl, wcat, bcat, qp2, pair, wpbt, bpb, pb,
                                  wpoA, WB, bpo, Wo, bo, bfused);

  rotate_k<<<1024, 256, 0, stream>>>(qp2, rot, trans, Acat, Bcat, VcatT, q2k2);

  attn_k<<<dim3(16, 4, 12), 256, 0, stream>>>(pb, Acat, Bcat, VcatT, q2k2, acc4);

  reduce_k<<<3648, 256, 0, stream>>>(acc4, AW);

  tail_gemm_k<<<dim3(8, 6, 4), 256, 0, stream>>>(AW, WB, outpre);

  ln_k<<<1024, 256, 0, stream>>>(single, outpre, bfused, lng, lnb, (float*)d_out);
}